// Round 20
// baseline (134.478 us; speedup 1.0000x reference)
//
#include <hip/hip_runtime.h>

#define N_NODES 1024
#define R_SRC   8192
#define E_DIM   1024
#define H_HEADS 4
#define DH_DIM  256
#define D_MAXN  48
#define NCONVB  1024   // grid-stride conversion blocks

typedef __attribute__((ext_vector_type(8))) short short8;
typedef __attribute__((ext_vector_type(4))) float f32x4;

__device__ __forceinline__ unsigned short f2bf(float f) {
    unsigned u = __float_as_uint(f);
    unsigned r = u + 0x7fffu + ((u >> 16) & 1u);   // round-to-nearest-even
    return (unsigned short)(r >> 16);
}
__device__ __forceinline__ float bf2f(unsigned short b) {
    return __uint_as_float(((unsigned)b) << 16);
}
__device__ __forceinline__ void gload16(const void* g, void* l) {
    __builtin_amdgcn_global_load_lds(
        (const __attribute__((address_space(1))) unsigned int*)g,
        (__attribute__((address_space(3))) unsigned int*)l,
        16, 0, 0);
}
template<int N> __device__ __forceinline__ void vwait() {
    if constexpr (N == 8)       asm volatile("s_waitcnt vmcnt(8)" ::: "memory");
    else if constexpr (N == 6)  asm volatile("s_waitcnt vmcnt(6)" ::: "memory");
    else if constexpr (N == 4)  asm volatile("s_waitcnt vmcnt(4)" ::: "memory");
    else if constexpr (N == 2)  asm volatile("s_waitcnt vmcnt(2)" ::: "memory");
    else                        asm volatile("s_waitcnt vmcnt(0)" ::: "memory");
}

// ===========================================================================
// Deep-pipelined bf16 MFMA NT GEMM, 128x256 tile, BK=64, 512 threads=8 waves.
// 3-buffer LDS rotation, issue-early staging, counted vmcnt, raw barriers.
// Used ONLY for the big src_relu GEMM (256 blocks, exact 1/CU fill).
// ===========================================================================
struct GD {
    const unsigned short* A;
    const unsigned short* B;
    const float* bias;
    void* C;
    int N, K, nbx, relu, outbf;
    const int* rowmask;
};

template<int BM, int BN>
__global__ __launch_bounds__(512) void gemm_t(GD d0, GD d1, int split)
{
    constexpr int AI = BM / 64;
    constexpr int BI = BN / 64;
    constexpr int VN = AI + BI;
    constexpr int FM = BM / 32;
    constexpr int FN = BN / 64;

    __shared__ __align__(16) unsigned short lds[3][(BM + BN) * 64];

    int bid = blockIdx.x;
    const int nwg = gridDim.x;
    bid = (bid & 7) * (nwg >> 3) + (bid >> 3);   // XCD swizzle (nwg%8==0)

    GD d; int q;
    if (bid < split) { d = d0; q = bid; }
    else             { d = d1; q = bid - split; }
    const int m0 = (q / d.nbx) * BM;
    const int n0 = (q % d.nbx) * BN;
    const int K  = d.K;

    const int t = threadIdx.x;
    const int w = t >> 6, l = t & 63;
    const int wm = w >> 2, wn = w & 3;

    const int trow = t >> 3, tkc = t & 7;
    const int tswz = tkc ^ (trow & 7);           // pre-swizzled global src
    const unsigned short* gA[AI];
    const unsigned short* gB[BI];
#pragma unroll
    for (int i = 0; i < AI; ++i)
        gA[i] = d.A + (size_t)(m0 + i * 64 + trow) * K + tswz * 8;
#pragma unroll
    for (int i = 0; i < BI; ++i)
        gB[i] = d.B + (size_t)(n0 + i * 64 + trow) * K + tswz * 8;

    f32x4 acc[FM][FN] = {};

    auto STAGE = [&](int c, int kt) {
        const int ko = kt * 64;
#pragma unroll
        for (int i = 0; i < AI; ++i)
            gload16(gA[i] + ko, &lds[c][(i * 512 + t) * 8]);
#pragma unroll
        for (int i = 0; i < BI; ++i)
            gload16(gB[i] + ko, &lds[c][BM * 64 + (i * 512 + t) * 8]);
    };

    const int nt = K / 64;
    STAGE(0, 0);
    STAGE(1, 1);
    vwait<VN>();
    __builtin_amdgcn_s_barrier();

    const int lr = l & 15, hi = l >> 4;
    const int rsw = l & 7;
    const int cs0 = ((0 + hi) ^ rsw) * 8;
    const int cs1 = ((4 + hi) ^ rsw) * 8;
    const int abase = (wm * (BM / 2) + lr) * 64;
    const int bbase = BM * 64 + (wn * 64 + lr) * 64;

    for (int kt = 0; kt < nt; ++kt) {
        const int cur = kt % 3;
        if (kt + 2 < nt) STAGE((kt + 2) % 3, kt + 2);   // issue-early

        const unsigned short* Ls = &lds[cur][0];

        short8 bv[FN][2];
#pragma unroll
        for (int fj = 0; fj < FN; ++fj) {
            bv[fj][0] = *(const short8*)&Ls[bbase + fj * 1024 + cs0];
            bv[fj][1] = *(const short8*)&Ls[bbase + fj * 1024 + cs1];
        }
#pragma unroll
        for (int g = 0; g < FM; g += 4) {
            short8 av[4][2];
#pragma unroll
            for (int fi = 0; fi < 4; ++fi) {
                av[fi][0] = *(const short8*)&Ls[abase + (g + fi) * 1024 + cs0];
                av[fi][1] = *(const short8*)&Ls[abase + (g + fi) * 1024 + cs1];
            }
            __builtin_amdgcn_s_setprio(1);
#pragma unroll
            for (int ks = 0; ks < 2; ++ks)
#pragma unroll
                for (int fi = 0; fi < 4; ++fi)
#pragma unroll
                    for (int fj = 0; fj < FN; ++fj)
                        acc[g + fi][fj] = __builtin_amdgcn_mfma_f32_16x16x32_bf16(
                            av[fi][ks], bv[fj][ks], acc[g + fi][fj], 0, 0, 0);
            __builtin_amdgcn_s_setprio(0);
        }

        asm volatile("" ::: "memory");
        __builtin_amdgcn_s_barrier();
        if (kt + 2 < nt) {
            vwait<VN>();
        } else {
            vwait<0>();
        }
        __builtin_amdgcn_s_barrier();
    }

#pragma unroll
    for (int fj = 0; fj < FN; ++fj) {
        const int c = n0 + wn * 64 + fj * 16 + lr;
        const float bvs = d.bias[c];
#pragma unroll
        for (int fi = 0; fi < FM; ++fi) {
            const int rb = m0 + wm * (BM / 2) + fi * 16 + hi * 4;
#pragma unroll
            for (int qq = 0; qq < 4; ++qq) {
                const int r = rb + qq;
                float x = acc[fi][fj][qq] + bvs;
                if (d.relu) x = fmaxf(x, 0.0f);
                if (d.rowmask && d.rowmask[r] == 0) x = 0.0f;
                if (d.outbf) ((unsigned short*)d.C)[(size_t)r * d.N + c] = f2bf(x);
                else         ((float*)d.C)[(size_t)r * d.N + c] = x;
            }
        }
    }
}

// ===========================================================================
// Pipelined strided small GEMM (64x64 tile, 256 threads, BK=32), 3-buffer
// rotation + issue-early + counted vmcnt(2) + raw barriers. Per-grid.z offs.
// ===========================================================================
struct GS {
    const unsigned short* A;
    const unsigned short* B;
    const float* bias;        // nullable
    void* C;
    int lda, ldb, ldc, K, relu, outbf;
    long long azs, bzs, czs;  // per-z element offsets
    int bias_zs;
    const int* rowmask;       // nullable (indexed by output row)
};

__global__ __launch_bounds__(256) void gemm_s(GS g)
{
    const int z = blockIdx.z;
    const unsigned short* A = g.A + (size_t)((long long)z * g.azs);
    const unsigned short* B = g.B + (size_t)((long long)z * g.bzs);
    const float* bias = g.bias ? g.bias + (size_t)z * g.bias_zs : nullptr;

    __shared__ __align__(16) unsigned short S[3][128 * 32];   // 24 KB

    const int t = threadIdx.x;
    const int m0 = blockIdx.y * 64;
    const int n0 = blockIdx.x * 64;
    const int w = t >> 6, l = t & 63;
    const int wrow = (w >> 1) * 32;
    const int wcol = (w & 1) * 32;
    const int lr = l & 15;
    const int kg = (l >> 4) * 8;

    f32x4 acc[2][2] = {};

    const unsigned short* gp0 = A + (size_t)(m0 + (t >> 2)) * g.lda + (t & 3) * 8;
    const unsigned short* gp1 = B + (size_t)(n0 + (t >> 2)) * g.ldb + (t & 3) * 8;

    auto STAGE = [&](int c, int k0) {
        gload16(gp0 + k0, &S[c][t * 8]);
        gload16(gp1 + k0, &S[c][2048 + t * 8]);
    };

    const int nt = g.K / 32;
    STAGE(0, 0);
    STAGE(1, 32);
    vwait<2>();
    __builtin_amdgcn_s_barrier();

    for (int kt = 0; kt < nt; ++kt) {
        const int cur = kt % 3;
        if (kt + 2 < nt) STAGE((kt + 2) % 3, (kt + 2) * 32);   // issue-early

        const unsigned short* Ls = &S[cur][0];

        short8 af[2], bw[2];
#pragma unroll
        for (int i = 0; i < 2; ++i)
            af[i] = *(const short8*)&Ls[(wrow + i * 16 + lr) * 32 + kg];
#pragma unroll
        for (int j = 0; j < 2; ++j)
            bw[j] = *(const short8*)&Ls[2048 + (wcol + j * 16 + lr) * 32 + kg];
#pragma unroll
        for (int i = 0; i < 2; ++i)
#pragma unroll
            for (int j = 0; j < 2; ++j)
                acc[i][j] = __builtin_amdgcn_mfma_f32_16x16x32_bf16(
                    af[i], bw[j], acc[i][j], 0, 0, 0);

        asm volatile("" ::: "memory");
        __builtin_amdgcn_s_barrier();
        if (kt + 2 < nt) {
            vwait<2>();
        } else {
            vwait<0>();
        }
        __builtin_amdgcn_s_barrier();
    }

#pragma unroll
    for (int j = 0; j < 2; ++j) {
        const int c = n0 + wcol + j * 16 + lr;
        const float bv = bias ? bias[c] : 0.0f;
#pragma unroll
        for (int i = 0; i < 2; ++i) {
            const int rbase = m0 + wrow + i * 16 + (l >> 4) * 4;
#pragma unroll
            for (int qq = 0; qq < 4; ++qq) {
                const int r = rbase + qq;
                float x = acc[i][j][qq] + bv;
                if (g.relu) x = fmaxf(x, 0.0f);
                if (g.rowmask && g.rowmask[r] == 0) x = 0.0f;
                if (g.outbf)
                    ((unsigned short*)g.C)[(size_t)((long long)z * g.czs) + (size_t)r * g.ldc + c] = f2bf(x);
                else
                    ((float*)g.C)[(size_t)((long long)z * g.czs) + (size_t)r * g.ldc + c] = x;
            }
        }
    }
}

// ---------------------------------------------------------------------------
// Fused pre-pass (Q GEMM removed -- folded into M = WqT@WkT downstream):
//   [0, 512)            : weight transposes -> WkT/WqT[h][e][d] bf16
//   [512, 516)          : bqk[h,e] = sum_d bq[hd] * Wk[hd, e]   (f32)
//   [516, 516+N)        : neighbor lists
//   [516+N, +NCONVB)    : fp32->bf16 conversions, grid-stride, 4 f4/thread
// Single UNION shared buffer (16.6 KB).
// ---------------------------------------------------------------------------
struct ConvArgs {
    const float* s[5];
    unsigned short* d[5];
    unsigned off[6];
};

__global__ __launch_bounds__(256) void pre_kernel(
    const float* __restrict__ adj, int* __restrict__ neigh, int* __restrict__ deg,
    ConvArgs a, const float* __restrict__ inw_f, const float* __restrict__ in_b,
    unsigned short* __restrict__ WkT, unsigned short* __restrict__ WqT,
    float* __restrict__ bqk)
{
    __shared__ __align__(16) unsigned char smem[64 * 65 * 4];   // 16.6 KB union
    const int t = threadIdx.x;

    if (blockIdx.x < 512) {
        // ---- weight transpose: tile 64(e) x 64(d) per block
        float (*tile)[65] = (float (*)[65])smem;
        const int is_k = blockIdx.x < 256;
        const int sub = blockIdx.x & 255;
        const int h = sub >> 6, rem = sub & 63;
        const int e0 = (rem >> 2) * 64, d0 = (rem & 3) * 64;
        const int rowbase = (is_k ? E_DIM : 0) + h * 256 + d0;
        const int r = t >> 2, c4 = (t & 3) * 16;
        const float* tsrc = inw_f + (size_t)(rowbase + r) * E_DIM + e0 + c4;
#pragma unroll
        for (int jj = 0; jj < 4; ++jj) {
            float4 v = ((const float4*)tsrc)[jj];
            tile[r][c4 + jj * 4 + 0] = v.x;
            tile[r][c4 + jj * 4 + 1] = v.y;
            tile[r][c4 + jj * 4 + 2] = v.z;
            tile[r][c4 + jj * 4 + 3] = v.w;
        }
        __syncthreads();
        const int er = t >> 2, dc = (t & 3) * 16;
        unsigned short* wout = (is_k ? WkT : WqT)
            + ((size_t)h * E_DIM + e0 + er) * 256 + d0 + dc;
#pragma unroll
        for (int jj = 0; jj < 4; ++jj) {
            ushort4 o;
            o.x = f2bf(tile[dc + jj * 4 + 0][er]);
            o.y = f2bf(tile[dc + jj * 4 + 1][er]);
            o.z = f2bf(tile[dc + jj * 4 + 2][er]);
            o.w = f2bf(tile[dc + jj * 4 + 3][er]);
            ((ushort4*)wout)[jj] = o;
        }
        return;
    }

    if (blockIdx.x < 516) {
        // ---- bqk[h,e] = sum_d bq[h*256+d] * Wk[h*256+d, e]
        const int h = blockIdx.x - 512;
        float acc[4] = {0.f, 0.f, 0.f, 0.f};
#pragma unroll 4
        for (int dd = 0; dd < 256; ++dd) {
            const float bv = in_b[h * 256 + dd];
            const float* row = inw_f + (size_t)(E_DIM + h * 256 + dd) * E_DIM;
#pragma unroll
            for (int j = 0; j < 4; ++j)
                acc[j] = fmaf(bv, row[t + j * 256], acc[j]);
        }
#pragma unroll
        for (int j = 0; j < 4; ++j) bqk[h * E_DIM + t + j * 256] = acc[j];
        return;
    }

    if (blockIdx.x < (unsigned)(516 + N_NODES)) {
        // ---- neighbor lists: 4 waves, wave w owns columns [w*2048,(w+1)*2048)
        int* s_cnt = (int*)smem;
        int (*s_idx)[D_MAXN] = (int (*)[D_MAXN])(smem + 16);

        const int n    = blockIdx.x - 516;
        const int w    = t >> 6;
        const int lane = t & 63;
        const float* row = adj + (size_t)n * R_SRC;

        const int seg0 = w * (R_SRC / 4);
        const unsigned long long lower = (1ULL << lane) - 1ULL;
        int total = 0;

        for (int base = seg0; base < seg0 + R_SRC / 4; base += 256) {
            const float v0 = row[base + lane];
            const float v1 = row[base + 64 + lane];
            const float v2 = row[base + 128 + lane];
            const float v3 = row[base + 192 + lane];
            const unsigned long long m0 = __ballot(v0 != 0.0f);
            const unsigned long long m1 = __ballot(v1 != 0.0f);
            const unsigned long long m2 = __ballot(v2 != 0.0f);
            const unsigned long long m3 = __ballot(v3 != 0.0f);
            int p;
            p = total + __popcll(m0 & lower);
            if (v0 != 0.0f && p < D_MAXN) s_idx[w][p] = base + lane;
            total += __popcll(m0);
            p = total + __popcll(m1 & lower);
            if (v1 != 0.0f && p < D_MAXN) s_idx[w][p] = base + 64 + lane;
            total += __popcll(m1);
            p = total + __popcll(m2 & lower);
            if (v2 != 0.0f && p < D_MAXN) s_idx[w][p] = base + 128 + lane;
            total += __popcll(m2);
            p = total + __popcll(m3 & lower);
            if (v3 != 0.0f && p < D_MAXN) s_idx[w][p] = base + 192 + lane;
            total += __popcll(m3);
        }
        if (lane == 0) s_cnt[w] = total;
        __syncthreads();

        int start = 0;
#pragma unroll
        for (int i = 0; i < 4; ++i) if (i < w) start += s_cnt[i];
        const int degree = s_cnt[0] + s_cnt[1] + s_cnt[2] + s_cnt[3];
        const int nstore = total < D_MAXN ? total : D_MAXN;
        if (lane < nstore) {
            const int gpos = start + lane;
            if (gpos < D_MAXN) neigh[n * D_MAXN + gpos] = s_idx[w][lane];
        }
        if (t == 0) deg[n] = degree;
        return;
    }

    // ---- conversions: grid-stride, 4 float4 per thread per iteration
    {
        const unsigned total = a.off[5];
        const unsigned stride = NCONVB * 1024;           // f4 per sweep
        for (unsigned bs = (blockIdx.x - 516 - N_NODES) * 1024; bs < total; bs += stride) {
            float4 v[4];
            unsigned idx[4];
            int ok[4];
#pragma unroll
            for (int j = 0; j < 4; ++j) {
                idx[j] = bs + j * 256 + t;
                ok[j] = idx[j] < total;
            }
            int seg[4];
#pragma unroll
            for (int j = 0; j < 4; ++j) {
                seg[j] = 0;
#pragma unroll
                for (int s = 1; s < 5; ++s) seg[j] += (idx[j] >= a.off[s]);
            }
#pragma unroll
            for (int j = 0; j < 4; ++j)
                if (ok[j]) v[j] = ((const float4*)a.s[seg[j]])[idx[j] - a.off[seg[j]]];
#pragma unroll
            for (int j = 0; j < 4; ++j) {
                if (ok[j]) {
                    ushort4 o;
                    o.x = f2bf(v[j].x); o.y = f2bf(v[j].y);
                    o.z = f2bf(v[j].z); o.w = f2bf(v[j].w);
                    ((ushort4*)a.d[seg[j]])[idx[j] - a.off[seg[j]]] = o;
                }
            }
        }
    }
}

// ---------------------------------------------------------------------------
// Fused per-edge scores + online softmax + context aggregation.
// Block = node, wave h = head, lane owns 16 contiguous dims. 2-edge unroll.
// ---------------------------------------------------------------------------
__global__ __launch_bounds__(256) void gather_ctx(
    const float* __restrict__ Ahat, const unsigned short* __restrict__ srcrel,
    const int* __restrict__ neigh, const int* __restrict__ deg,
    unsigned short* __restrict__ ctx)
{
    const int n = blockIdx.x;
    const int t = threadIdx.x;
    const int h = t >> 6;
    const int lane = t & 63;

    unsigned short* crow = ctx + ((size_t)n * H_HEADS + h) * E_DIM + lane * 16;
    const int degree = deg[n];
    if (degree == 0) {
        ushort4 z4 = {0, 0, 0, 0};
#pragma unroll
        for (int j = 0; j < 4; ++j) ((ushort4*)crow)[j] = z4;
        return;
    }
    const int dv = degree < D_MAXN ? degree : D_MAXN;

    __shared__ int s_neigh[D_MAXN];
    if (t < dv) s_neigh[t] = neigh[n * D_MAXN + t];
    __syncthreads();

    float a[16];
    {
        const float4* ap = (const float4*)(Ahat + (size_t)n * (H_HEADS * E_DIM) + h * E_DIM + lane * 16);
#pragma unroll
        for (int j = 0; j < 4; ++j) {
            float4 v = ap[j];
            a[j * 4 + 0] = v.x; a[j * 4 + 1] = v.y; a[j * 4 + 2] = v.z; a[j * 4 + 3] = v.w;
        }
    }

    float m = -3.4e38f, sum = 0.0f;
    float cacc[16];
#pragma unroll
    for (int i = 0; i < 16; ++i) cacc[i] = 0.0f;

    const float scale = 0.0625f;   // 1/sqrt(256)

    int d = 0;
    for (; d + 1 < dv; d += 2) {
        const ushort4* rp0 = (const ushort4*)(srcrel + (size_t)s_neigh[d]     * E_DIM + lane * 16);
        const ushort4* rp1 = (const ushort4*)(srcrel + (size_t)s_neigh[d + 1] * E_DIM + lane * 16);
        ushort4 w00 = rp0[0], w01 = rp0[1], w02 = rp0[2], w03 = rp0[3];
        ushort4 w10 = rp1[0], w11 = rp1[1], w12 = rp1[2], w13 = rp1[3];
        float e0[16], e1[16];
        e0[0]=bf2f(w00.x); e0[1]=bf2f(w00.y); e0[2]=bf2f(w00.z); e0[3]=bf2f(w00.w);
        e0[4]=bf2f(w01.x); e0[5]=bf2f(w01.y); e0[6]=bf2f(w01.z); e0[7]=bf2f(w01.w);
        e0[8]=bf2f(w02.x); e0[9]=bf2f(w02.y); e0[10]=bf2f(w02.z); e0[11]=bf2f(w02.w);
        e0[12]=bf2f(w03.x); e0[13]=bf2f(w03.y); e0[14]=bf2f(w03.z); e0[15]=bf2f(w03.w);
        e1[0]=bf2f(w10.x); e1[1]=bf2f(w10.y); e1[2]=bf2f(w10.z); e1[3]=bf2f(w10.w);
        e1[4]=bf2f(w11.x); e1[5]=bf2f(w11.y); e1[6]=bf2f(w11.z); e1[7]=bf2f(w11.w);
        e1[8]=bf2f(w12.x); e1[9]=bf2f(w12.y); e1[10]=bf2f(w12.z); e1[11]=bf2f(w12.w);
        e1[12]=bf2f(w13.x); e1[13]=bf2f(w13.y); e1[14]=bf2f(w13.z); e1[15]=bf2f(w13.w);

        float s0 = 0.0f, s1 = 0.0f;
#pragma unroll
        for (int i = 0; i < 16; ++i) { s0 = fmaf(a[i], e0[i], s0); s1 = fmaf(a[i], e1[i], s1); }
#pragma unroll
        for (int off = 32; off > 0; off >>= 1) {
            s0 += __shfl_xor(s0, off);
            s1 += __shfl_xor(s1, off);
        }
        s0 *= scale; s1 *= scale;

        if (s0 > m) {
            const float f = __expf(m - s0);
            sum *= f;
#pragma unroll
            for (int i = 0; i < 16; ++i) cacc[i] *= f;
            m = s0;
        }
        {
            const float wgt = __expf(s0 - m);
            sum += wgt;
#pragma unroll
            for (int i = 0; i < 16; ++i) cacc[i] = fmaf(wgt, e0[i], cacc[i]);
        }
        if (s1 > m) {
            const float f = __expf(m - s1);
            sum *= f;
#pragma unroll
            for (int i = 0; i < 16; ++i) cacc[i] *= f;
            m = s1;
        }
        {
            const float wgt = __expf(s1 - m);
            sum += wgt;
#pragma unroll
            for (int i = 0; i < 16; ++i) cacc[i] = fmaf(wgt, e1[i], cacc[i]);
        }
    }
    for (; d < dv; ++d) {
        const ushort4* rp = (const ushort4*)(srcrel + (size_t)s_neigh[d] * E_DIM + lane * 16);
        float e[16];
#pragma unroll
        for (int j = 0; j < 4; ++j) {
            ushort4 v = rp[j];
            e[j * 4 + 0] = bf2f(v.x); e[j * 4 + 1] = bf2f(v.y);
            e[j * 4 + 2] = bf2f(v.z); e[j * 4 + 3] = bf2f(v.w);
        }
        float s = 0.0f;
#pragma unroll
        for (int i = 0; i < 16; ++i) s = fmaf(a[i], e[i], s);
#pragma unroll
        for (int off = 32; off > 0; off >>= 1) s += __shfl_xor(s, off);
        s *= scale;
        if (s > m) {
            const float f = __expf(m - s);
            sum *= f;
#pragma unroll
            for (int i = 0; i < 16; ++i) cacc[i] *= f;
            m = s;
        }
        const float wgt = __expf(s - m);
        sum += wgt;
#pragma unroll
        for (int i = 0; i < 16; ++i) cacc[i] = fmaf(wgt, e[i], cacc[i]);
    }

    const float inv = 1.0f / sum;
#pragma unroll
    for (int j = 0; j < 4; ++j) {
        ushort4 o;
        o.x = f2bf(cacc[j * 4 + 0] * inv);
        o.y = f2bf(cacc[j * 4 + 1] * inv);
        o.z = f2bf(cacc[j * 4 + 2] * inv);
        o.w = f2bf(cacc[j * 4 + 3] * inv);
        ((ushort4*)crow)[j] = o;
    }
}

// ---------------------------------------------------------------------------
extern "C" void kernel_launch(void* const* d_in, const int* in_sizes, int n_in,
                              void* d_out, int out_size, void* d_ws, size_t ws_size,
                              hipStream_t stream)
{
    const float* target  = (const float*)d_in[0];   // [N, E]
    const float* source  = (const float*)d_in[1];   // [R, E]
    const float* adj     = (const float*)d_in[2];   // [N, R]
    const float* W_trans = (const float*)d_in[3];   // [E, E]
    const float* b_trans = (const float*)d_in[4];   // [E]
    const float* in_w    = (const float*)d_in[5];   // [3E, E]
    const float* in_b    = (const float*)d_in[6];   // [3E]
    const float* out_w   = (const float*)d_in[7];   // [E, E]
    const float* out_b   = (const float*)d_in[8];   // [E]
    float* out = (float*)d_out;                     // [N, E] f32

    char* ws = (char*)d_ws;
    unsigned short* src_bf    = (unsigned short*)ws; ws += (size_t)R_SRC * E_DIM * 2;
    unsigned short* wt_bf     = (unsigned short*)ws; ws += (size_t)E_DIM * E_DIM * 2;
    unsigned short* wv_bf     = (unsigned short*)ws; ws += (size_t)E_DIM * E_DIM * 2;
    unsigned short* outw_bf   = (unsigned short*)ws; ws += (size_t)E_DIM * E_DIM * 2;
    unsigned short* tgt_bf    = (unsigned short*)ws; ws += (size_t)N_NODES * E_DIM * 2;
    unsigned short* srcrel_bf = (unsigned short*)ws; ws += (size_t)R_SRC * E_DIM * 2;
    unsigned short* WkT_bf    = (unsigned short*)ws; ws += (size_t)H_HEADS * E_DIM * DH_DIM * 2;
    unsigned short* WqT_bf    = (unsigned short*)ws; ws += (size_t)H_HEADS * E_DIM * DH_DIM * 2;
    unsigned short* M_bf      = (unsigned short*)ws; ws += (size_t)H_HEADS * E_DIM * E_DIM * 2;
    float*          bqk       = (float*)ws;          ws += (size_t)H_HEADS * E_DIM * 4;
    float*          Ahat      = (float*)ws;          ws += (size_t)N_NODES * H_HEADS * E_DIM * 4;
    unsigned short* ctx_bf    = (unsigned short*)ws; ws += (size_t)N_NODES * H_HEADS * E_DIM * 2;
    unsigned short* attn_bf   = (unsigned short*)ws; ws += (size_t)N_NODES * E_DIM * 2;
    int*            neigh     = (int*)ws;            ws += (size_t)N_NODES * D_MAXN * 4;
    int*            deg       = (int*)ws;            ws += (size_t)N_NODES * 4;

    const size_t EE = (size_t)E_DIM * E_DIM;

    // 1) pre-pass: WkT/WqT transposes + bqk + neighbor lists + conversions
    {
        ConvArgs a;
        const unsigned sz4[5] = {
            (unsigned)((size_t)R_SRC * E_DIM / 4),
            (unsigned)(EE / 4),
            (unsigned)(EE / 4),
            (unsigned)(EE / 4),
            (unsigned)((size_t)N_NODES * E_DIM / 4)};
        a.s[0] = source;        a.d[0] = src_bf;
        a.s[1] = W_trans;       a.d[1] = wt_bf;
        a.s[2] = in_w + 2 * EE; a.d[2] = wv_bf;     // Wv
        a.s[3] = out_w;         a.d[3] = outw_bf;
        a.s[4] = target;        a.d[4] = tgt_bf;
        a.off[0] = 0;
        for (int i = 0; i < 5; ++i) a.off[i + 1] = a.off[i] + sz4[i];
        pre_kernel<<<516 + N_NODES + NCONVB, 256, 0, stream>>>(
            adj, neigh, deg, a, in_w, in_b, WkT_bf, WqT_bf, bqk);
    }

    // 2) src_relu = relu(source @ W_trans^T + b_trans)  [R, E] bf16 (256 blk)
    {
        GD ds;
        ds.A = src_bf; ds.B = wt_bf; ds.bias = b_trans; ds.C = srcrel_bf;
        ds.N = E_DIM; ds.K = E_DIM; ds.nbx = E_DIM / 256; ds.relu = 1; ds.outbf = 1;
        ds.rowmask = nullptr;
        const int sblocks = (R_SRC / 128) * (E_DIM / 256);   // 256
        gemm_t<128, 256><<<sblocks, 512, 0, stream>>>(ds, ds, sblocks);
    }

    // 3) M_h[e,e'] = sum_d Wk[hd,e] * Wq[hd,e']   [H, E, E] bf16  (K=256)
    {
        GS g;
        g.A = WkT_bf; g.B = WqT_bf; g.bias = nullptr; g.C = M_bf;
        g.lda = DH_DIM; g.ldb = DH_DIM; g.ldc = E_DIM; g.K = DH_DIM;
        g.relu = 0; g.outbf = 1;
        g.azs = (long long)E_DIM * DH_DIM;
        g.bzs = (long long)E_DIM * DH_DIM;
        g.czs = (long long)E_DIM * E_DIM;
        g.bias_zs = 0; g.rowmask = nullptr;
        gemm_s<<<dim3(E_DIM / 64, E_DIM / 64, H_HEADS), 256, 0, stream>>>(g);
    }

    // 4) Ahat[n,h,e] = sum_e' target[n,e'] * M_h[e,e'] + bqk[h,e]  (K=1024)
    {
        GS g;
        g.A = tgt_bf; g.B = M_bf; g.bias = bqk; g.C = Ahat;
        g.lda = E_DIM; g.ldb = E_DIM; g.ldc = H_HEADS * E_DIM; g.K = E_DIM;
        g.relu = 0; g.outbf = 0;
        g.azs = 0;
        g.bzs = (long long)E_DIM * E_DIM;
        g.czs = E_DIM;
        g.bias_zs = E_DIM; g.rowmask = nullptr;
        gemm_s<<<dim3(E_DIM / 64, N_NODES / 64, H_HEADS), 256, 0, stream>>>(g);
    }

    // 5) per-edge scores + softmax + ctx aggregation  [N, H, E] bf16
    gather_ctx<<<N_NODES, 256, 0, stream>>>(Ahat, srcrel_bf, neigh, deg, ctx_bf);

    // 6) attn_h = CTX_h @ Wv_h^T + bv_h   [N, E] bf16
    {
        GS g;
        g.A = ctx_bf; g.B = wv_bf; g.bias = in_b + 2 * E_DIM; g.C = attn_bf;
        g.lda = H_HEADS * E_DIM; g.ldb = E_DIM; g.ldc = E_DIM; g.K = E_DIM;
        g.relu = 0; g.outbf = 1;
        g.azs = E_DIM;
        g.bzs = (long long)DH_DIM * E_DIM;
        g.czs = DH_DIM;
        g.bias_zs = DH_DIM; g.rowmask = nullptr;
        gemm_s<<<dim3(DH_DIM / 64, N_NODES / 64, H_HEADS), 256, 0, stream>>>(g);
    }

    // 7) out = attn @ out_w^T + out_b, deg==0 rows zeroed  [N, E] f32
    {
        GS g;
        g.A = attn_bf; g.B = outw_bf; g.bias = out_b; g.C = out;
        g.lda = E_DIM; g.ldb = E_DIM; g.ldc = E_DIM; g.K = E_DIM;
        g.relu = 0; g.outbf = 0; g.azs = 0; g.bzs = 0; g.czs = 0; g.bias_zs = 0;
        g.rowmask = deg;
        gemm_s<<<dim3(E_DIM / 64, N_NODES / 64, 1), 256, 0, stream>>>(g);
    }
}

// Round 21
// 106.100 us; speedup vs baseline: 1.2675x; 1.2675x over previous
//
#include <hip/hip_runtime.h>

#define N_NODES 1024
#define R_SRC   8192
#define E_DIM   1024
#define H_HEADS 4
#define DH_DIM  256
#define D_MAXN  48
#define NCONVB  1024   // grid-stride conversion blocks

typedef __attribute__((ext_vector_type(8))) short short8;
typedef __attribute__((ext_vector_type(4))) float f32x4;

__device__ __forceinline__ unsigned short f2bf(float f) {
    unsigned u = __float_as_uint(f);
    unsigned r = u + 0x7fffu + ((u >> 16) & 1u);   // round-to-nearest-even
    return (unsigned short)(r >> 16);
}
__device__ __forceinline__ float bf2f(unsigned short b) {
    return __uint_as_float(((unsigned)b) << 16);
}
__device__ __forceinline__ void gload16(const void* g, void* l) {
    __builtin_amdgcn_global_load_lds(
        (const __attribute__((address_space(1))) unsigned int*)g,
        (__attribute__((address_space(3))) unsigned int*)l,
        16, 0, 0);
}
template<int N> __device__ __forceinline__ void vwait() {
    if constexpr (N == 8)       asm volatile("s_waitcnt vmcnt(8)" ::: "memory");
    else if constexpr (N == 6)  asm volatile("s_waitcnt vmcnt(6)" ::: "memory");
    else if constexpr (N == 4)  asm volatile("s_waitcnt vmcnt(4)" ::: "memory");
    else if constexpr (N == 2)  asm volatile("s_waitcnt vmcnt(2)" ::: "memory");
    else                        asm volatile("s_waitcnt vmcnt(0)" ::: "memory");
}

// ===========================================================================
// Deep-pipelined bf16 MFMA NT GEMM, 128x256 tile, BK=64, 512 threads=8 waves.
// 3-buffer LDS rotation, issue-early staging, counted vmcnt, raw barriers.
// Used ONLY for the big src_relu GEMM (256 blocks, exact 1/CU fill).
// ===========================================================================
struct GD {
    const unsigned short* A;
    const unsigned short* B;
    const float* bias;
    void* C;
    int N, K, nbx, relu, outbf;
    const int* rowmask;
};

template<int BM, int BN>
__global__ __launch_bounds__(512) void gemm_t(GD d0, GD d1, int split)
{
    constexpr int AI = BM / 64;
    constexpr int BI = BN / 64;
    constexpr int VN = AI + BI;
    constexpr int FM = BM / 32;
    constexpr int FN = BN / 64;

    __shared__ __align__(16) unsigned short lds[3][(BM + BN) * 64];

    int bid = blockIdx.x;
    const int nwg = gridDim.x;
    bid = (bid & 7) * (nwg >> 3) + (bid >> 3);   // XCD swizzle (nwg%8==0)

    GD d; int q;
    if (bid < split) { d = d0; q = bid; }
    else             { d = d1; q = bid - split; }
    const int m0 = (q / d.nbx) * BM;
    const int n0 = (q % d.nbx) * BN;
    const int K  = d.K;

    const int t = threadIdx.x;
    const int w = t >> 6, l = t & 63;
    const int wm = w >> 2, wn = w & 3;

    const int trow = t >> 3, tkc = t & 7;
    const int tswz = tkc ^ (trow & 7);           // pre-swizzled global src
    const unsigned short* gA[AI];
    const unsigned short* gB[BI];
#pragma unroll
    for (int i = 0; i < AI; ++i)
        gA[i] = d.A + (size_t)(m0 + i * 64 + trow) * K + tswz * 8;
#pragma unroll
    for (int i = 0; i < BI; ++i)
        gB[i] = d.B + (size_t)(n0 + i * 64 + trow) * K + tswz * 8;

    f32x4 acc[FM][FN] = {};

    auto STAGE = [&](int c, int kt) {
        const int ko = kt * 64;
#pragma unroll
        for (int i = 0; i < AI; ++i)
            gload16(gA[i] + ko, &lds[c][(i * 512 + t) * 8]);
#pragma unroll
        for (int i = 0; i < BI; ++i)
            gload16(gB[i] + ko, &lds[c][BM * 64 + (i * 512 + t) * 8]);
    };

    const int nt = K / 64;
    STAGE(0, 0);
    STAGE(1, 1);
    vwait<VN>();
    __builtin_amdgcn_s_barrier();

    const int lr = l & 15, hi = l >> 4;
    const int rsw = l & 7;
    const int cs0 = ((0 + hi) ^ rsw) * 8;
    const int cs1 = ((4 + hi) ^ rsw) * 8;
    const int abase = (wm * (BM / 2) + lr) * 64;
    const int bbase = BM * 64 + (wn * 64 + lr) * 64;

    for (int kt = 0; kt < nt; ++kt) {
        const int cur = kt % 3;
        if (kt + 2 < nt) STAGE((kt + 2) % 3, kt + 2);   // issue-early

        const unsigned short* Ls = &lds[cur][0];

        short8 bv[FN][2];
#pragma unroll
        for (int fj = 0; fj < FN; ++fj) {
            bv[fj][0] = *(const short8*)&Ls[bbase + fj * 1024 + cs0];
            bv[fj][1] = *(const short8*)&Ls[bbase + fj * 1024 + cs1];
        }
#pragma unroll
        for (int g = 0; g < FM; g += 4) {
            short8 av[4][2];
#pragma unroll
            for (int fi = 0; fi < 4; ++fi) {
                av[fi][0] = *(const short8*)&Ls[abase + (g + fi) * 1024 + cs0];
                av[fi][1] = *(const short8*)&Ls[abase + (g + fi) * 1024 + cs1];
            }
            __builtin_amdgcn_s_setprio(1);
#pragma unroll
            for (int ks = 0; ks < 2; ++ks)
#pragma unroll
                for (int fi = 0; fi < 4; ++fi)
#pragma unroll
                    for (int fj = 0; fj < FN; ++fj)
                        acc[g + fi][fj] = __builtin_amdgcn_mfma_f32_16x16x32_bf16(
                            av[fi][ks], bv[fj][ks], acc[g + fi][fj], 0, 0, 0);
            __builtin_amdgcn_s_setprio(0);
        }

        asm volatile("" ::: "memory");
        __builtin_amdgcn_s_barrier();
        if (kt + 2 < nt) {
            vwait<VN>();
        } else {
            vwait<0>();
        }
        __builtin_amdgcn_s_barrier();
    }

#pragma unroll
    for (int fj = 0; fj < FN; ++fj) {
        const int c = n0 + wn * 64 + fj * 16 + lr;
        const float bvs = d.bias[c];
#pragma unroll
        for (int fi = 0; fi < FM; ++fi) {
            const int rb = m0 + wm * (BM / 2) + fi * 16 + hi * 4;
#pragma unroll
            for (int qq = 0; qq < 4; ++qq) {
                const int r = rb + qq;
                float x = acc[fi][fj][qq] + bvs;
                if (d.relu) x = fmaxf(x, 0.0f);
                if (d.rowmask && d.rowmask[r] == 0) x = 0.0f;
                if (d.outbf) ((unsigned short*)d.C)[(size_t)r * d.N + c] = f2bf(x);
                else         ((float*)d.C)[(size_t)r * d.N + c] = x;
            }
        }
    }
}

// ===========================================================================
// Pipelined strided small GEMM (64x64 tile, 256 threads, BK=32), 3-buffer
// rotation + issue-early + counted vmcnt(2) + raw barriers. Per-grid.z offs.
// ===========================================================================
struct GS {
    const unsigned short* A;
    const unsigned short* B;
    const float* bias;        // nullable
    void* C;
    int lda, ldb, ldc, K, relu, outbf;
    long long azs, bzs, czs;  // per-z element offsets
    int bias_zs;
    const int* rowmask;       // nullable (indexed by output row)
};

__global__ __launch_bounds__(256) void gemm_s(GS g)
{
    const int z = blockIdx.z;
    const unsigned short* A = g.A + (size_t)((long long)z * g.azs);
    const unsigned short* B = g.B + (size_t)((long long)z * g.bzs);
    const float* bias = g.bias ? g.bias + (size_t)z * g.bias_zs : nullptr;

    __shared__ __align__(16) unsigned short S[3][128 * 32];   // 24 KB

    const int t = threadIdx.x;
    const int m0 = blockIdx.y * 64;
    const int n0 = blockIdx.x * 64;
    const int w = t >> 6, l = t & 63;
    const int wrow = (w >> 1) * 32;
    const int wcol = (w & 1) * 32;
    const int lr = l & 15;
    const int kg = (l >> 4) * 8;

    f32x4 acc[2][2] = {};

    const unsigned short* gp0 = A + (size_t)(m0 + (t >> 2)) * g.lda + (t & 3) * 8;
    const unsigned short* gp1 = B + (size_t)(n0 + (t >> 2)) * g.ldb + (t & 3) * 8;

    auto STAGE = [&](int c, int k0) {
        gload16(gp0 + k0, &S[c][t * 8]);
        gload16(gp1 + k0, &S[c][2048 + t * 8]);
    };

    const int nt = g.K / 32;
    STAGE(0, 0);
    STAGE(1, 32);
    vwait<2>();
    __builtin_amdgcn_s_barrier();

    for (int kt = 0; kt < nt; ++kt) {
        const int cur = kt % 3;
        if (kt + 2 < nt) STAGE((kt + 2) % 3, (kt + 2) * 32);   // issue-early

        const unsigned short* Ls = &S[cur][0];

        short8 af[2], bw[2];
#pragma unroll
        for (int i = 0; i < 2; ++i)
            af[i] = *(const short8*)&Ls[(wrow + i * 16 + lr) * 32 + kg];
#pragma unroll
        for (int j = 0; j < 2; ++j)
            bw[j] = *(const short8*)&Ls[2048 + (wcol + j * 16 + lr) * 32 + kg];
#pragma unroll
        for (int i = 0; i < 2; ++i)
#pragma unroll
            for (int j = 0; j < 2; ++j)
                acc[i][j] = __builtin_amdgcn_mfma_f32_16x16x32_bf16(
                    af[i], bw[j], acc[i][j], 0, 0, 0);

        asm volatile("" ::: "memory");
        __builtin_amdgcn_s_barrier();
        if (kt + 2 < nt) {
            vwait<2>();
        } else {
            vwait<0>();
        }
        __builtin_amdgcn_s_barrier();
    }

#pragma unroll
    for (int j = 0; j < 2; ++j) {
        const int c = n0 + wcol + j * 16 + lr;
        const float bv = bias ? bias[c] : 0.0f;
#pragma unroll
        for (int i = 0; i < 2; ++i) {
            const int rbase = m0 + wrow + i * 16 + (l >> 4) * 4;
#pragma unroll
            for (int qq = 0; qq < 4; ++qq) {
                const int r = rbase + qq;
                float x = acc[i][j][qq] + bv;
                if (g.relu) x = fmaxf(x, 0.0f);
                if (g.rowmask && g.rowmask[r] == 0) x = 0.0f;
                if (g.outbf)
                    ((unsigned short*)g.C)[(size_t)((long long)z * g.czs) + (size_t)r * g.ldc + c] = f2bf(x);
                else
                    ((float*)g.C)[(size_t)((long long)z * g.czs) + (size_t)r * g.ldc + c] = x;
            }
        }
    }
}

// ---------------------------------------------------------------------------
// Fused pre-pass (round-16/18 form -- measured best). Heavy blocks FIRST:
//   [0, 256)           : Q = target @ Wq^T + bq (fp32-direct, 64x64, BK=32)
//   [256, 512)         : Wk transpose -> WkT[h][e][d] bf16
//   [512, 512+N)       : neighbor lists
//   [512+N, +NCONVB)   : fp32->bf16 conversions, grid-stride, 4 f4/thread
// Single UNION shared buffer (16.6 KB).
// ---------------------------------------------------------------------------
struct ConvArgs {
    const float* s[4];
    unsigned short* d[4];
    unsigned off[5];
};

__global__ __launch_bounds__(256) void pre_kernel(
    const float* __restrict__ adj, int* __restrict__ neigh, int* __restrict__ deg,
    ConvArgs a, const float* __restrict__ inw_f, const float* __restrict__ tgt_f,
    const float* __restrict__ in_b, unsigned short* __restrict__ WkT,
    unsigned short* __restrict__ Q_bf)
{
    __shared__ __align__(16) unsigned char smem[64 * 65 * 4];   // 16.6 KB union
    const int t = threadIdx.x;

    if (blockIdx.x < 256) {
        // ---- Q GEMM (fp32 direct): 64x64 tile, K=1024, BK=32
        unsigned short (*QS)[64 * 32] = (unsigned short (*)[64 * 32])smem;
        const int qb = blockIdx.x;
        const int m0 = (qb >> 4) * 64;
        const int n0 = (qb & 15) * 64;
        const int w = t >> 6, l = t & 63;
        const int wrow = (w >> 1) * 32;
        const int wcol = (w & 1) * 32;
        const int lr = l & 15;
        const int kg = (l >> 4) * 8;
        const int row = t >> 2, k8 = (t & 3) * 8;

        const float* ga = tgt_f + (size_t)(m0 + row) * E_DIM + k8;
        const float* gb = inw_f + (size_t)(n0 + row) * E_DIM + k8;   // Wq rows

        f32x4 acc[2][2] = {};

        for (int k0 = 0; k0 < E_DIM; k0 += 32) {
            float4 a0 = *(const float4*)(ga + k0);
            float4 a1 = *(const float4*)(ga + k0 + 4);
            float4 b0 = *(const float4*)(gb + k0);
            float4 b1 = *(const float4*)(gb + k0 + 4);
            short8 av, bv;
            av[0] = (short)f2bf(a0.x); av[1] = (short)f2bf(a0.y);
            av[2] = (short)f2bf(a0.z); av[3] = (short)f2bf(a0.w);
            av[4] = (short)f2bf(a1.x); av[5] = (short)f2bf(a1.y);
            av[6] = (short)f2bf(a1.z); av[7] = (short)f2bf(a1.w);
            bv[0] = (short)f2bf(b0.x); bv[1] = (short)f2bf(b0.y);
            bv[2] = (short)f2bf(b0.z); bv[3] = (short)f2bf(b0.w);
            bv[4] = (short)f2bf(b1.x); bv[5] = (short)f2bf(b1.y);
            bv[6] = (short)f2bf(b1.z); bv[7] = (short)f2bf(b1.w);
            *(short8*)&QS[0][row * 32 + k8] = av;
            *(short8*)&QS[1][row * 32 + k8] = bv;
            __syncthreads();

            short8 af[2], bw[2];
#pragma unroll
            for (int i = 0; i < 2; ++i)
                af[i] = *(const short8*)&QS[0][(wrow + i * 16 + lr) * 32 + kg];
#pragma unroll
            for (int j = 0; j < 2; ++j)
                bw[j] = *(const short8*)&QS[1][(wcol + j * 16 + lr) * 32 + kg];
#pragma unroll
            for (int i = 0; i < 2; ++i)
#pragma unroll
                for (int j = 0; j < 2; ++j)
                    acc[i][j] = __builtin_amdgcn_mfma_f32_16x16x32_bf16(
                        af[i], bw[j], acc[i][j], 0, 0, 0);
            __syncthreads();
        }

#pragma unroll
        for (int j = 0; j < 2; ++j) {
            const int c = n0 + wcol + j * 16 + lr;
            const float bv = in_b[c];
#pragma unroll
            for (int i = 0; i < 2; ++i) {
                const int rbase = m0 + wrow + i * 16 + (l >> 4) * 4;
#pragma unroll
                for (int qq = 0; qq < 4; ++qq)
                    Q_bf[(size_t)(rbase + qq) * E_DIM + c] = f2bf(acc[i][j][qq] + bv);
            }
        }
        return;
    }

    if (blockIdx.x < 512) {
        // ---- Wk transpose: tile 64(e) x 64(d) per block
        float (*tile)[65] = (float (*)[65])smem;
        const int tb = blockIdx.x - 256;
        const int h = tb >> 6, rem = tb & 63;
        const int e0 = (rem >> 2) * 64, d0 = (rem & 3) * 64;
        const int r = t >> 2, c4 = (t & 3) * 16;
        const float* tsrc = inw_f + (size_t)(E_DIM + h * 256 + d0 + r) * E_DIM + e0 + c4;
#pragma unroll
        for (int jj = 0; jj < 4; ++jj) {
            float4 v = ((const float4*)tsrc)[jj];
            tile[r][c4 + jj * 4 + 0] = v.x;
            tile[r][c4 + jj * 4 + 1] = v.y;
            tile[r][c4 + jj * 4 + 2] = v.z;
            tile[r][c4 + jj * 4 + 3] = v.w;
        }
        __syncthreads();
        const int er = t >> 2, dc = (t & 3) * 16;
        unsigned short* wout = WkT + ((size_t)h * E_DIM + e0 + er) * 256 + d0 + dc;
#pragma unroll
        for (int jj = 0; jj < 4; ++jj) {
            ushort4 o;
            o.x = f2bf(tile[dc + jj * 4 + 0][er]);
            o.y = f2bf(tile[dc + jj * 4 + 1][er]);
            o.z = f2bf(tile[dc + jj * 4 + 2][er]);
            o.w = f2bf(tile[dc + jj * 4 + 3][er]);
            ((ushort4*)wout)[jj] = o;
        }
        return;
    }

    if (blockIdx.x < (unsigned)(512 + N_NODES)) {
        // ---- neighbor lists: 4 waves, wave w owns columns [w*2048,(w+1)*2048)
        int* s_cnt = (int*)smem;
        int (*s_idx)[D_MAXN] = (int (*)[D_MAXN])(smem + 16);

        const int n    = blockIdx.x - 512;
        const int w    = t >> 6;
        const int lane = t & 63;
        const float* row = adj + (size_t)n * R_SRC;

        const int seg0 = w * (R_SRC / 4);
        const unsigned long long lower = (1ULL << lane) - 1ULL;
        int total = 0;

        for (int base = seg0; base < seg0 + R_SRC / 4; base += 256) {
            const float v0 = row[base + lane];
            const float v1 = row[base + 64 + lane];
            const float v2 = row[base + 128 + lane];
            const float v3 = row[base + 192 + lane];
            const unsigned long long m0 = __ballot(v0 != 0.0f);
            const unsigned long long m1 = __ballot(v1 != 0.0f);
            const unsigned long long m2 = __ballot(v2 != 0.0f);
            const unsigned long long m3 = __ballot(v3 != 0.0f);
            int p;
            p = total + __popcll(m0 & lower);
            if (v0 != 0.0f && p < D_MAXN) s_idx[w][p] = base + lane;
            total += __popcll(m0);
            p = total + __popcll(m1 & lower);
            if (v1 != 0.0f && p < D_MAXN) s_idx[w][p] = base + 64 + lane;
            total += __popcll(m1);
            p = total + __popcll(m2 & lower);
            if (v2 != 0.0f && p < D_MAXN) s_idx[w][p] = base + 128 + lane;
            total += __popcll(m2);
            p = total + __popcll(m3 & lower);
            if (v3 != 0.0f && p < D_MAXN) s_idx[w][p] = base + 192 + lane;
            total += __popcll(m3);
        }
        if (lane == 0) s_cnt[w] = total;
        __syncthreads();

        int start = 0;
#pragma unroll
        for (int i = 0; i < 4; ++i) if (i < w) start += s_cnt[i];
        const int degree = s_cnt[0] + s_cnt[1] + s_cnt[2] + s_cnt[3];
        const int nstore = total < D_MAXN ? total : D_MAXN;
        if (lane < nstore) {
            const int gpos = start + lane;
            if (gpos < D_MAXN) neigh[n * D_MAXN + gpos] = s_idx[w][lane];
        }
        if (t == 0) deg[n] = degree;
        return;
    }

    // ---- conversions: grid-stride, 4 float4 per thread per iteration
    {
        const unsigned total = a.off[4];
        const unsigned stride = NCONVB * 1024;           // f4 per sweep
        for (unsigned bs = (blockIdx.x - 512 - N_NODES) * 1024; bs < total; bs += stride) {
            float4 v[4];
            unsigned idx[4];
            int ok[4];
#pragma unroll
            for (int j = 0; j < 4; ++j) {
                idx[j] = bs + j * 256 + t;
                ok[j] = idx[j] < total;
            }
            int seg[4];
#pragma unroll
            for (int j = 0; j < 4; ++j) {
                seg[j] = 0;
#pragma unroll
                for (int s = 1; s < 4; ++s) seg[j] += (idx[j] >= a.off[s]);
            }
#pragma unroll
            for (int j = 0; j < 4; ++j)
                if (ok[j]) v[j] = ((const float4*)a.s[seg[j]])[idx[j] - a.off[seg[j]]];
#pragma unroll
            for (int j = 0; j < 4; ++j) {
                if (ok[j]) {
                    ushort4 o;
                    o.x = f2bf(v[j].x); o.y = f2bf(v[j].y);
                    o.z = f2bf(v[j].z); o.w = f2bf(v[j].w);
                    ((ushort4*)a.d[seg[j]])[idx[j] - a.off[seg[j]]] = o;
                }
            }
        }
    }
}

// ---------------------------------------------------------------------------
// Fused per-edge scores + online softmax + context aggregation.
// Block = node, wave h = head, lane owns 16 contiguous dims. 2-edge unroll.
// ---------------------------------------------------------------------------
__global__ __launch_bounds__(256) void gather_ctx(
    const float* __restrict__ Ahat, const unsigned short* __restrict__ srcrel,
    const int* __restrict__ neigh, const int* __restrict__ deg,
    unsigned short* __restrict__ ctx)
{
    const int n = blockIdx.x;
    const int t = threadIdx.x;
    const int h = t >> 6;
    const int lane = t & 63;

    unsigned short* crow = ctx + ((size_t)n * H_HEADS + h) * E_DIM + lane * 16;
    const int degree = deg[n];
    if (degree == 0) {
        ushort4 z4 = {0, 0, 0, 0};
#pragma unroll
        for (int j = 0; j < 4; ++j) ((ushort4*)crow)[j] = z4;
        return;
    }
    const int dv = degree < D_MAXN ? degree : D_MAXN;

    __shared__ int s_neigh[D_MAXN];
    if (t < dv) s_neigh[t] = neigh[n * D_MAXN + t];
    __syncthreads();

    float a[16];
    {
        const float4* ap = (const float4*)(Ahat + (size_t)n * (H_HEADS * E_DIM) + h * E_DIM + lane * 16);
#pragma unroll
        for (int j = 0; j < 4; ++j) {
            float4 v = ap[j];
            a[j * 4 + 0] = v.x; a[j * 4 + 1] = v.y; a[j * 4 + 2] = v.z; a[j * 4 + 3] = v.w;
        }
    }

    float m = -3.4e38f, sum = 0.0f;
    float cacc[16];
#pragma unroll
    for (int i = 0; i < 16; ++i) cacc[i] = 0.0f;

    const float scale = 0.0625f;   // 1/sqrt(256)

    int d = 0;
    for (; d + 1 < dv; d += 2) {
        const ushort4* rp0 = (const ushort4*)(srcrel + (size_t)s_neigh[d]     * E_DIM + lane * 16);
        const ushort4* rp1 = (const ushort4*)(srcrel + (size_t)s_neigh[d + 1] * E_DIM + lane * 16);
        ushort4 w00 = rp0[0], w01 = rp0[1], w02 = rp0[2], w03 = rp0[3];
        ushort4 w10 = rp1[0], w11 = rp1[1], w12 = rp1[2], w13 = rp1[3];
        float e0[16], e1[16];
        e0[0]=bf2f(w00.x); e0[1]=bf2f(w00.y); e0[2]=bf2f(w00.z); e0[3]=bf2f(w00.w);
        e0[4]=bf2f(w01.x); e0[5]=bf2f(w01.y); e0[6]=bf2f(w01.z); e0[7]=bf2f(w01.w);
        e0[8]=bf2f(w02.x); e0[9]=bf2f(w02.y); e0[10]=bf2f(w02.z); e0[11]=bf2f(w02.w);
        e0[12]=bf2f(w03.x); e0[13]=bf2f(w03.y); e0[14]=bf2f(w03.z); e0[15]=bf2f(w03.w);
        e1[0]=bf2f(w10.x); e1[1]=bf2f(w10.y); e1[2]=bf2f(w10.z); e1[3]=bf2f(w10.w);
        e1[4]=bf2f(w11.x); e1[5]=bf2f(w11.y); e1[6]=bf2f(w11.z); e1[7]=bf2f(w11.w);
        e1[8]=bf2f(w12.x); e1[9]=bf2f(w12.y); e1[10]=bf2f(w12.z); e1[11]=bf2f(w12.w);
        e1[12]=bf2f(w13.x); e1[13]=bf2f(w13.y); e1[14]=bf2f(w13.z); e1[15]=bf2f(w13.w);

        float s0 = 0.0f, s1 = 0.0f;
#pragma unroll
        for (int i = 0; i < 16; ++i) { s0 = fmaf(a[i], e0[i], s0); s1 = fmaf(a[i], e1[i], s1); }
#pragma unroll
        for (int off = 32; off > 0; off >>= 1) {
            s0 += __shfl_xor(s0, off);
            s1 += __shfl_xor(s1, off);
        }
        s0 *= scale; s1 *= scale;

        if (s0 > m) {
            const float f = __expf(m - s0);
            sum *= f;
#pragma unroll
            for (int i = 0; i < 16; ++i) cacc[i] *= f;
            m = s0;
        }
        {
            const float wgt = __expf(s0 - m);
            sum += wgt;
#pragma unroll
            for (int i = 0; i < 16; ++i) cacc[i] = fmaf(wgt, e0[i], cacc[i]);
        }
        if (s1 > m) {
            const float f = __expf(m - s1);
            sum *= f;
#pragma unroll
            for (int i = 0; i < 16; ++i) cacc[i] *= f;
            m = s1;
        }
        {
            const float wgt = __expf(s1 - m);
            sum += wgt;
#pragma unroll
            for (int i = 0; i < 16; ++i) cacc[i] = fmaf(wgt, e1[i], cacc[i]);
        }
    }
    for (; d < dv; ++d) {
        const ushort4* rp = (const ushort4*)(srcrel + (size_t)s_neigh[d] * E_DIM + lane * 16);
        float e[16];
#pragma unroll
        for (int j = 0; j < 4; ++j) {
            ushort4 v = rp[j];
            e[j * 4 + 0] = bf2f(v.x); e[j * 4 + 1] = bf2f(v.y);
            e[j * 4 + 2] = bf2f(v.z); e[j * 4 + 3] = bf2f(v.w);
        }
        float s = 0.0f;
#pragma unroll
        for (int i = 0; i < 16; ++i) s = fmaf(a[i], e[i], s);
#pragma unroll
        for (int off = 32; off > 0; off >>= 1) s += __shfl_xor(s, off);
        s *= scale;
        if (s > m) {
            const float f = __expf(m - s);
            sum *= f;
#pragma unroll
            for (int i = 0; i < 16; ++i) cacc[i] *= f;
            m = s;
        }
        const float wgt = __expf(s - m);
        sum += wgt;
#pragma unroll
        for (int i = 0; i < 16; ++i) cacc[i] = fmaf(wgt, e[i], cacc[i]);
    }

    const float inv = 1.0f / sum;
#pragma unroll
    for (int j = 0; j < 4; ++j) {
        ushort4 o;
        o.x = f2bf(cacc[j * 4 + 0] * inv);
        o.y = f2bf(cacc[j * 4 + 1] * inv);
        o.z = f2bf(cacc[j * 4 + 2] * inv);
        o.w = f2bf(cacc[j * 4 + 3] * inv);
        ((ushort4*)crow)[j] = o;
    }
}

// ---------------------------------------------------------------------------
extern "C" void kernel_launch(void* const* d_in, const int* in_sizes, int n_in,
                              void* d_out, int out_size, void* d_ws, size_t ws_size,
                              hipStream_t stream)
{
    const float* target  = (const float*)d_in[0];   // [N, E]
    const float* source  = (const float*)d_in[1];   // [R, E]
    const float* adj     = (const float*)d_in[2];   // [N, R]
    const float* W_trans = (const float*)d_in[3];   // [E, E]
    const float* b_trans = (const float*)d_in[4];   // [E]
    const float* in_w    = (const float*)d_in[5];   // [3E, E]
    const float* in_b    = (const float*)d_in[6];   // [3E]
    const float* out_w   = (const float*)d_in[7];   // [E, E]
    const float* out_b   = (const float*)d_in[8];   // [E]
    float* out = (float*)d_out;                     // [N, E] f32

    char* ws = (char*)d_ws;
    unsigned short* src_bf    = (unsigned short*)ws; ws += (size_t)R_SRC * E_DIM * 2;
    unsigned short* wt_bf     = (unsigned short*)ws; ws += (size_t)E_DIM * E_DIM * 2;
    unsigned short* wv_bf     = (unsigned short*)ws; ws += (size_t)E_DIM * E_DIM * 2;
    unsigned short* outw_bf   = (unsigned short*)ws; ws += (size_t)E_DIM * E_DIM * 2;
    unsigned short* srcrel_bf = (unsigned short*)ws; ws += (size_t)R_SRC * E_DIM * 2;
    unsigned short* WkT_bf    = (unsigned short*)ws; ws += (size_t)H_HEADS * E_DIM * DH_DIM * 2;
    unsigned short* Q_bf      = (unsigned short*)ws; ws += (size_t)N_NODES * E_DIM * 2;
    float*          Ahat      = (float*)ws;         ws += (size_t)N_NODES * H_HEADS * E_DIM * 4;
    unsigned short* ctx_bf    = (unsigned short*)ws; ws += (size_t)N_NODES * H_HEADS * E_DIM * 2;
    unsigned short* attn_bf   = (unsigned short*)ws; ws += (size_t)N_NODES * E_DIM * 2;
    int*            neigh     = (int*)ws;            ws += (size_t)N_NODES * D_MAXN * 4;
    int*            deg       = (int*)ws;            ws += (size_t)N_NODES * 4;

    const size_t EE = (size_t)E_DIM * E_DIM;

    // 1) pre-pass: Q GEMM + WkT transpose first, then neigh lists, then convs
    {
        ConvArgs a;
        const unsigned sz4[4] = {
            (unsigned)((size_t)R_SRC * E_DIM / 4),
            (unsigned)(EE / 4),
            (unsigned)(EE / 4),
            (unsigned)(EE / 4)};
        a.s[0] = source;        a.d[0] = src_bf;
        a.s[1] = W_trans;       a.d[1] = wt_bf;
        a.s[2] = in_w + 2 * EE; a.d[2] = wv_bf;     // Wv
        a.s[3] = out_w;         a.d[3] = outw_bf;
        a.off[0] = 0;
        for (int i = 0; i < 4; ++i) a.off[i + 1] = a.off[i] + sz4[i];
        pre_kernel<<<512 + N_NODES + NCONVB, 256, 0, stream>>>(
            adj, neigh, deg, a, in_w, target, in_b, WkT_bf, Q_bf);
    }

    // 2) src_relu = relu(source @ W_trans^T + b_trans)  [R, E] bf16 (256 blk)
    {
        GD ds;
        ds.A = src_bf; ds.B = wt_bf; ds.bias = b_trans; ds.C = srcrel_bf;
        ds.N = E_DIM; ds.K = E_DIM; ds.nbx = E_DIM / 256; ds.relu = 1; ds.outbf = 1;
        ds.rowmask = nullptr;
        const int sblocks = (R_SRC / 128) * (E_DIM / 256);   // 256
        gemm_t<128, 256><<<sblocks, 512, 0, stream>>>(ds, ds, sblocks);
    }

    // 3) Ahat_h = Q_h @ WkT_h   [N, H, E] f32  (K=256, no bias; bk cancels)
    {
        GS g;
        g.A = Q_bf; g.B = WkT_bf; g.bias = nullptr; g.C = Ahat;
        g.lda = E_DIM; g.ldb = DH_DIM; g.ldc = H_HEADS * E_DIM; g.K = DH_DIM;
        g.relu = 0; g.outbf = 0;
        g.azs = DH_DIM;
        g.bzs = (long long)E_DIM * DH_DIM;
        g.czs = E_DIM;
        g.bias_zs = 0; g.rowmask = nullptr;
        gemm_s<<<dim3(E_DIM / 64, N_NODES / 64, H_HEADS), 256, 0, stream>>>(g);
    }

    // 4) per-edge scores + softmax + ctx aggregation  [N, H, E] bf16
    gather_ctx<<<N_NODES, 256, 0, stream>>>(Ahat, srcrel_bf, neigh, deg, ctx_bf);

    // 5) attn_h = CTX_h @ Wv_h^T + bv_h   [N, E] bf16
    {
        GS g;
        g.A = ctx_bf; g.B = wv_bf; g.bias = in_b + 2 * E_DIM; g.C = attn_bf;
        g.lda = H_HEADS * E_DIM; g.ldb = E_DIM; g.ldc = E_DIM; g.K = E_DIM;
        g.relu = 0; g.outbf = 1;
        g.azs = E_DIM;
        g.bzs = (long long)DH_DIM * E_DIM;
        g.czs = DH_DIM;
        g.bias_zs = DH_DIM; g.rowmask = nullptr;
        gemm_s<<<dim3(DH_DIM / 64, N_NODES / 64, H_HEADS), 256, 0, stream>>>(g);
    }

    // 6) out = attn @ out_w^T + out_b, deg==0 rows zeroed  [N, E] f32
    {
        GS g;
        g.A = attn_bf; g.B = outw_bf; g.bias = out_b; g.C = out;
        g.lda = E_DIM; g.ldb = E_DIM; g.ldc = E_DIM; g.K = E_DIM;
        g.relu = 0; g.outbf = 0; g.azs = 0; g.bzs = 0; g.czs = 0; g.bias_zs = 0;
        g.rowmask = deg;
        gemm_s<<<dim3(E_DIM / 64, N_NODES / 64, 1), 256, 0, stream>>>(g);
    }
}

// Round 22
// 105.027 us; speedup vs baseline: 1.2804x; 1.0102x over previous
//
#include <hip/hip_runtime.h>

#define N_NODES 1024
#define R_SRC   8192
#define E_DIM   1024
#define H_HEADS 4
#define DH_DIM  256
#define D_MAXN  48
#define NCONVB  2048   // grid-stride conversion blocks (finer tail balance)

typedef __attribute__((ext_vector_type(8))) short short8;
typedef __attribute__((ext_vector_type(4))) float f32x4;

__device__ __forceinline__ unsigned short f2bf(float f) {
    unsigned u = __float_as_uint(f);
    unsigned r = u + 0x7fffu + ((u >> 16) & 1u);   // round-to-nearest-even
    return (unsigned short)(r >> 16);
}
__device__ __forceinline__ float bf2f(unsigned short b) {
    return __uint_as_float(((unsigned)b) << 16);
}
__device__ __forceinline__ void gload16(const void* g, void* l) {
    __builtin_amdgcn_global_load_lds(
        (const __attribute__((address_space(1))) unsigned int*)g,
        (__attribute__((address_space(3))) unsigned int*)l,
        16, 0, 0);
}
template<int N> __device__ __forceinline__ void vwait() {
    if constexpr (N == 8)       asm volatile("s_waitcnt vmcnt(8)" ::: "memory");
    else if constexpr (N == 6)  asm volatile("s_waitcnt vmcnt(6)" ::: "memory");
    else if constexpr (N == 4)  asm volatile("s_waitcnt vmcnt(4)" ::: "memory");
    else if constexpr (N == 2)  asm volatile("s_waitcnt vmcnt(2)" ::: "memory");
    else                        asm volatile("s_waitcnt vmcnt(0)" ::: "memory");
}

// ===========================================================================
// Deep-pipelined bf16 MFMA NT GEMM, 128x256 tile, BK=64, 512 threads=8 waves.
// 3-buffer LDS rotation, issue-early staging, counted vmcnt, raw barriers.
// Used ONLY for the big src_relu GEMM (256 blocks, exact 1/CU fill).
// ===========================================================================
struct GD {
    const unsigned short* A;
    const unsigned short* B;
    const float* bias;
    void* C;
    int N, K, nbx, relu, outbf;
    const int* rowmask;
};

template<int BM, int BN>
__global__ __launch_bounds__(512) void gemm_t(GD d0, GD d1, int split)
{
    constexpr int AI = BM / 64;
    constexpr int BI = BN / 64;
    constexpr int VN = AI + BI;
    constexpr int FM = BM / 32;
    constexpr int FN = BN / 64;

    __shared__ __align__(16) unsigned short lds[3][(BM + BN) * 64];

    int bid = blockIdx.x;
    const int nwg = gridDim.x;
    bid = (bid & 7) * (nwg >> 3) + (bid >> 3);   // XCD swizzle (nwg%8==0)

    GD d; int q;
    if (bid < split) { d = d0; q = bid; }
    else             { d = d1; q = bid - split; }
    const int m0 = (q / d.nbx) * BM;
    const int n0 = (q % d.nbx) * BN;
    const int K  = d.K;

    const int t = threadIdx.x;
    const int w = t >> 6, l = t & 63;
    const int wm = w >> 2, wn = w & 3;

    const int trow = t >> 3, tkc = t & 7;
    const int tswz = tkc ^ (trow & 7);           // pre-swizzled global src
    const unsigned short* gA[AI];
    const unsigned short* gB[BI];
#pragma unroll
    for (int i = 0; i < AI; ++i)
        gA[i] = d.A + (size_t)(m0 + i * 64 + trow) * K + tswz * 8;
#pragma unroll
    for (int i = 0; i < BI; ++i)
        gB[i] = d.B + (size_t)(n0 + i * 64 + trow) * K + tswz * 8;

    f32x4 acc[FM][FN] = {};

    auto STAGE = [&](int c, int kt) {
        const int ko = kt * 64;
#pragma unroll
        for (int i = 0; i < AI; ++i)
            gload16(gA[i] + ko, &lds[c][(i * 512 + t) * 8]);
#pragma unroll
        for (int i = 0; i < BI; ++i)
            gload16(gB[i] + ko, &lds[c][BM * 64 + (i * 512 + t) * 8]);
    };

    const int nt = K / 64;
    STAGE(0, 0);
    STAGE(1, 1);
    vwait<VN>();
    __builtin_amdgcn_s_barrier();

    const int lr = l & 15, hi = l >> 4;
    const int rsw = l & 7;
    const int cs0 = ((0 + hi) ^ rsw) * 8;
    const int cs1 = ((4 + hi) ^ rsw) * 8;
    const int abase = (wm * (BM / 2) + lr) * 64;
    const int bbase = BM * 64 + (wn * 64 + lr) * 64;

    for (int kt = 0; kt < nt; ++kt) {
        const int cur = kt % 3;
        if (kt + 2 < nt) STAGE((kt + 2) % 3, kt + 2);   // issue-early

        const unsigned short* Ls = &lds[cur][0];

        short8 bv[FN][2];
#pragma unroll
        for (int fj = 0; fj < FN; ++fj) {
            bv[fj][0] = *(const short8*)&Ls[bbase + fj * 1024 + cs0];
            bv[fj][1] = *(const short8*)&Ls[bbase + fj * 1024 + cs1];
        }
#pragma unroll
        for (int g = 0; g < FM; g += 4) {
            short8 av[4][2];
#pragma unroll
            for (int fi = 0; fi < 4; ++fi) {
                av[fi][0] = *(const short8*)&Ls[abase + (g + fi) * 1024 + cs0];
                av[fi][1] = *(const short8*)&Ls[abase + (g + fi) * 1024 + cs1];
            }
            __builtin_amdgcn_s_setprio(1);
#pragma unroll
            for (int ks = 0; ks < 2; ++ks)
#pragma unroll
                for (int fi = 0; fi < 4; ++fi)
#pragma unroll
                    for (int fj = 0; fj < FN; ++fj)
                        acc[g + fi][fj] = __builtin_amdgcn_mfma_f32_16x16x32_bf16(
                            av[fi][ks], bv[fj][ks], acc[g + fi][fj], 0, 0, 0);
            __builtin_amdgcn_s_setprio(0);
        }

        asm volatile("" ::: "memory");
        __builtin_amdgcn_s_barrier();
        if (kt + 2 < nt) {
            vwait<VN>();
        } else {
            vwait<0>();
        }
        __builtin_amdgcn_s_barrier();
    }

#pragma unroll
    for (int fj = 0; fj < FN; ++fj) {
        const int c = n0 + wn * 64 + fj * 16 + lr;
        const float bvs = d.bias[c];
#pragma unroll
        for (int fi = 0; fi < FM; ++fi) {
            const int rb = m0 + wm * (BM / 2) + fi * 16 + hi * 4;
#pragma unroll
            for (int qq = 0; qq < 4; ++qq) {
                const int r = rb + qq;
                float x = acc[fi][fj][qq] + bvs;
                if (d.relu) x = fmaxf(x, 0.0f);
                if (d.rowmask && d.rowmask[r] == 0) x = 0.0f;
                if (d.outbf) ((unsigned short*)d.C)[(size_t)r * d.N + c] = f2bf(x);
                else         ((float*)d.C)[(size_t)r * d.N + c] = x;
            }
        }
    }
}

// ===========================================================================
// Pipelined strided small GEMM (64x64 tile, 256 threads, BK=32), 3-buffer
// rotation + issue-early + counted vmcnt(2) + raw barriers. Per-grid.z offs.
// ===========================================================================
struct GS {
    const unsigned short* A;
    const unsigned short* B;
    const float* bias;        // nullable
    void* C;
    int lda, ldb, ldc, K, relu, outbf;
    long long azs, bzs, czs;  // per-z element offsets
    int bias_zs;
    const int* rowmask;       // nullable (indexed by output row)
};

__global__ __launch_bounds__(256) void gemm_s(GS g)
{
    const int z = blockIdx.z;
    const unsigned short* A = g.A + (size_t)((long long)z * g.azs);
    const unsigned short* B = g.B + (size_t)((long long)z * g.bzs);
    const float* bias = g.bias ? g.bias + (size_t)z * g.bias_zs : nullptr;

    __shared__ __align__(16) unsigned short S[3][128 * 32];   // 24 KB

    const int t = threadIdx.x;
    const int m0 = blockIdx.y * 64;
    const int n0 = blockIdx.x * 64;
    const int w = t >> 6, l = t & 63;
    const int wrow = (w >> 1) * 32;
    const int wcol = (w & 1) * 32;
    const int lr = l & 15;
    const int kg = (l >> 4) * 8;

    f32x4 acc[2][2] = {};

    const unsigned short* gp0 = A + (size_t)(m0 + (t >> 2)) * g.lda + (t & 3) * 8;
    const unsigned short* gp1 = B + (size_t)(n0 + (t >> 2)) * g.ldb + (t & 3) * 8;

    auto STAGE = [&](int c, int k0) {
        gload16(gp0 + k0, &S[c][t * 8]);
        gload16(gp1 + k0, &S[c][2048 + t * 8]);
    };

    const int nt = g.K / 32;
    STAGE(0, 0);
    STAGE(1, 32);
    vwait<2>();
    __builtin_amdgcn_s_barrier();

    for (int kt = 0; kt < nt; ++kt) {
        const int cur = kt % 3;
        if (kt + 2 < nt) STAGE((kt + 2) % 3, (kt + 2) * 32);   // issue-early

        const unsigned short* Ls = &S[cur][0];

        short8 af[2], bw[2];
#pragma unroll
        for (int i = 0; i < 2; ++i)
            af[i] = *(const short8*)&Ls[(wrow + i * 16 + lr) * 32 + kg];
#pragma unroll
        for (int j = 0; j < 2; ++j)
            bw[j] = *(const short8*)&Ls[2048 + (wcol + j * 16 + lr) * 32 + kg];
#pragma unroll
        for (int i = 0; i < 2; ++i)
#pragma unroll
            for (int j = 0; j < 2; ++j)
                acc[i][j] = __builtin_amdgcn_mfma_f32_16x16x32_bf16(
                    af[i], bw[j], acc[i][j], 0, 0, 0);

        asm volatile("" ::: "memory");
        __builtin_amdgcn_s_barrier();
        if (kt + 2 < nt) {
            vwait<2>();
        } else {
            vwait<0>();
        }
        __builtin_amdgcn_s_barrier();
    }

#pragma unroll
    for (int j = 0; j < 2; ++j) {
        const int c = n0 + wcol + j * 16 + lr;
        const float bv = bias ? bias[c] : 0.0f;
#pragma unroll
        for (int i = 0; i < 2; ++i) {
            const int rbase = m0 + wrow + i * 16 + (l >> 4) * 4;
#pragma unroll
            for (int qq = 0; qq < 4; ++qq) {
                const int r = rbase + qq;
                float x = acc[i][j][qq] + bv;
                if (g.relu) x = fmaxf(x, 0.0f);
                if (g.rowmask && g.rowmask[r] == 0) x = 0.0f;
                if (g.outbf)
                    ((unsigned short*)g.C)[(size_t)((long long)z * g.czs) + (size_t)r * g.ldc + c] = f2bf(x);
                else
                    ((float*)g.C)[(size_t)((long long)z * g.czs) + (size_t)r * g.ldc + c] = x;
            }
        }
    }
}

// ---------------------------------------------------------------------------
// Fused pre-pass (round-16/18 form -- measured best). Heavy blocks FIRST:
//   [0, 256)           : Q = target @ Wq^T + bq (fp32-direct, 64x64, BK=32)
//   [256, 512)         : Wk transpose -> WkT[h][e][d] bf16
//   [512, 512+N)       : neighbor lists
//   [512+N, +NCONVB)   : fp32->bf16 conversions, grid-stride, 4 f4/thread
// Single UNION shared buffer (16.6 KB).
// ---------------------------------------------------------------------------
struct ConvArgs {
    const float* s[4];
    unsigned short* d[4];
    unsigned off[5];
};

__global__ __launch_bounds__(256) void pre_kernel(
    const float* __restrict__ adj, int* __restrict__ neigh, int* __restrict__ deg,
    ConvArgs a, const float* __restrict__ inw_f, const float* __restrict__ tgt_f,
    const float* __restrict__ in_b, unsigned short* __restrict__ WkT,
    unsigned short* __restrict__ Q_bf)
{
    __shared__ __align__(16) unsigned char smem[64 * 65 * 4];   // 16.6 KB union
    const int t = threadIdx.x;

    if (blockIdx.x < 256) {
        // ---- Q GEMM (fp32 direct): 64x64 tile, K=1024, BK=32
        unsigned short (*QS)[64 * 32] = (unsigned short (*)[64 * 32])smem;
        const int qb = blockIdx.x;
        const int m0 = (qb >> 4) * 64;
        const int n0 = (qb & 15) * 64;
        const int w = t >> 6, l = t & 63;
        const int wrow = (w >> 1) * 32;
        const int wcol = (w & 1) * 32;
        const int lr = l & 15;
        const int kg = (l >> 4) * 8;
        const int row = t >> 2, k8 = (t & 3) * 8;

        const float* ga = tgt_f + (size_t)(m0 + row) * E_DIM + k8;
        const float* gb = inw_f + (size_t)(n0 + row) * E_DIM + k8;   // Wq rows

        f32x4 acc[2][2] = {};

        for (int k0 = 0; k0 < E_DIM; k0 += 32) {
            float4 a0 = *(const float4*)(ga + k0);
            float4 a1 = *(const float4*)(ga + k0 + 4);
            float4 b0 = *(const float4*)(gb + k0);
            float4 b1 = *(const float4*)(gb + k0 + 4);
            short8 av, bv;
            av[0] = (short)f2bf(a0.x); av[1] = (short)f2bf(a0.y);
            av[2] = (short)f2bf(a0.z); av[3] = (short)f2bf(a0.w);
            av[4] = (short)f2bf(a1.x); av[5] = (short)f2bf(a1.y);
            av[6] = (short)f2bf(a1.z); av[7] = (short)f2bf(a1.w);
            bv[0] = (short)f2bf(b0.x); bv[1] = (short)f2bf(b0.y);
            bv[2] = (short)f2bf(b0.z); bv[3] = (short)f2bf(b0.w);
            bv[4] = (short)f2bf(b1.x); bv[5] = (short)f2bf(b1.y);
            bv[6] = (short)f2bf(b1.z); bv[7] = (short)f2bf(b1.w);
            *(short8*)&QS[0][row * 32 + k8] = av;
            *(short8*)&QS[1][row * 32 + k8] = bv;
            __syncthreads();

            short8 af[2], bw[2];
#pragma unroll
            for (int i = 0; i < 2; ++i)
                af[i] = *(const short8*)&QS[0][(wrow + i * 16 + lr) * 32 + kg];
#pragma unroll
            for (int j = 0; j < 2; ++j)
                bw[j] = *(const short8*)&QS[1][(wcol + j * 16 + lr) * 32 + kg];
#pragma unroll
            for (int i = 0; i < 2; ++i)
#pragma unroll
                for (int j = 0; j < 2; ++j)
                    acc[i][j] = __builtin_amdgcn_mfma_f32_16x16x32_bf16(
                        af[i], bw[j], acc[i][j], 0, 0, 0);
            __syncthreads();
        }

#pragma unroll
        for (int j = 0; j < 2; ++j) {
            const int c = n0 + wcol + j * 16 + lr;
            const float bv = in_b[c];
#pragma unroll
            for (int i = 0; i < 2; ++i) {
                const int rbase = m0 + wrow + i * 16 + (l >> 4) * 4;
#pragma unroll
                for (int qq = 0; qq < 4; ++qq)
                    Q_bf[(size_t)(rbase + qq) * E_DIM + c] = f2bf(acc[i][j][qq] + bv);
            }
        }
        return;
    }

    if (blockIdx.x < 512) {
        // ---- Wk transpose: tile 64(e) x 64(d) per block
        float (*tile)[65] = (float (*)[65])smem;
        const int tb = blockIdx.x - 256;
        const int h = tb >> 6, rem = tb & 63;
        const int e0 = (rem >> 2) * 64, d0 = (rem & 3) * 64;
        const int r = t >> 2, c4 = (t & 3) * 16;
        const float* tsrc = inw_f + (size_t)(E_DIM + h * 256 + d0 + r) * E_DIM + e0 + c4;
#pragma unroll
        for (int jj = 0; jj < 4; ++jj) {
            float4 v = ((const float4*)tsrc)[jj];
            tile[r][c4 + jj * 4 + 0] = v.x;
            tile[r][c4 + jj * 4 + 1] = v.y;
            tile[r][c4 + jj * 4 + 2] = v.z;
            tile[r][c4 + jj * 4 + 3] = v.w;
        }
        __syncthreads();
        const int er = t >> 2, dc = (t & 3) * 16;
        unsigned short* wout = WkT + ((size_t)h * E_DIM + e0 + er) * 256 + d0 + dc;
#pragma unroll
        for (int jj = 0; jj < 4; ++jj) {
            ushort4 o;
            o.x = f2bf(tile[dc + jj * 4 + 0][er]);
            o.y = f2bf(tile[dc + jj * 4 + 1][er]);
            o.z = f2bf(tile[dc + jj * 4 + 2][er]);
            o.w = f2bf(tile[dc + jj * 4 + 3][er]);
            ((ushort4*)wout)[jj] = o;
        }
        return;
    }

    if (blockIdx.x < (unsigned)(512 + N_NODES)) {
        // ---- neighbor lists: 4 waves, wave w owns columns [w*2048,(w+1)*2048)
        int* s_cnt = (int*)smem;
        int (*s_idx)[D_MAXN] = (int (*)[D_MAXN])(smem + 16);

        const int n    = blockIdx.x - 512;
        const int w    = t >> 6;
        const int lane = t & 63;
        const float* row = adj + (size_t)n * R_SRC;

        const int seg0 = w * (R_SRC / 4);
        const unsigned long long lower = (1ULL << lane) - 1ULL;
        int total = 0;

        for (int base = seg0; base < seg0 + R_SRC / 4; base += 256) {
            const float v0 = row[base + lane];
            const float v1 = row[base + 64 + lane];
            const float v2 = row[base + 128 + lane];
            const float v3 = row[base + 192 + lane];
            const unsigned long long m0 = __ballot(v0 != 0.0f);
            const unsigned long long m1 = __ballot(v1 != 0.0f);
            const unsigned long long m2 = __ballot(v2 != 0.0f);
            const unsigned long long m3 = __ballot(v3 != 0.0f);
            int p;
            p = total + __popcll(m0 & lower);
            if (v0 != 0.0f && p < D_MAXN) s_idx[w][p] = base + lane;
            total += __popcll(m0);
            p = total + __popcll(m1 & lower);
            if (v1 != 0.0f && p < D_MAXN) s_idx[w][p] = base + 64 + lane;
            total += __popcll(m1);
            p = total + __popcll(m2 & lower);
            if (v2 != 0.0f && p < D_MAXN) s_idx[w][p] = base + 128 + lane;
            total += __popcll(m2);
            p = total + __popcll(m3 & lower);
            if (v3 != 0.0f && p < D_MAXN) s_idx[w][p] = base + 192 + lane;
            total += __popcll(m3);
        }
        if (lane == 0) s_cnt[w] = total;
        __syncthreads();

        int start = 0;
#pragma unroll
        for (int i = 0; i < 4; ++i) if (i < w) start += s_cnt[i];
        const int degree = s_cnt[0] + s_cnt[1] + s_cnt[2] + s_cnt[3];
        const int nstore = total < D_MAXN ? total : D_MAXN;
        if (lane < nstore) {
            const int gpos = start + lane;
            if (gpos < D_MAXN) neigh[n * D_MAXN + gpos] = s_idx[w][lane];
        }
        if (t == 0) deg[n] = degree;
        return;
    }

    // ---- conversions: grid-stride, 4 float4 per thread per iteration
    {
        const unsigned total = a.off[4];
        const unsigned stride = NCONVB * 1024;           // f4 per sweep
        for (unsigned bs = (blockIdx.x - 512 - N_NODES) * 1024; bs < total; bs += stride) {
            float4 v[4];
            unsigned idx[4];
            int ok[4];
#pragma unroll
            for (int j = 0; j < 4; ++j) {
                idx[j] = bs + j * 256 + t;
                ok[j] = idx[j] < total;
            }
            int seg[4];
#pragma unroll
            for (int j = 0; j < 4; ++j) {
                seg[j] = 0;
#pragma unroll
                for (int s = 1; s < 4; ++s) seg[j] += (idx[j] >= a.off[s]);
            }
#pragma unroll
            for (int j = 0; j < 4; ++j)
                if (ok[j]) v[j] = ((const float4*)a.s[seg[j]])[idx[j] - a.off[seg[j]]];
#pragma unroll
            for (int j = 0; j < 4; ++j) {
                if (ok[j]) {
                    ushort4 o;
                    o.x = f2bf(v[j].x); o.y = f2bf(v[j].y);
                    o.z = f2bf(v[j].z); o.w = f2bf(v[j].w);
                    ((ushort4*)a.d[seg[j]])[idx[j] - a.off[seg[j]]] = o;
                }
            }
        }
    }
}

// ---------------------------------------------------------------------------
// Fused per-edge scores + online softmax + context aggregation.
// Block = node, wave h = head, lane owns 16 contiguous dims. 2-edge unroll.
// Ahat is bf16 (halves its HBM traffic; softmax margin tolerates rounding).
// ---------------------------------------------------------------------------
__global__ __launch_bounds__(256) void gather_ctx(
    const unsigned short* __restrict__ Ahat, const unsigned short* __restrict__ srcrel,
    const int* __restrict__ neigh, const int* __restrict__ deg,
    unsigned short* __restrict__ ctx)
{
    const int n = blockIdx.x;
    const int t = threadIdx.x;
    const int h = t >> 6;
    const int lane = t & 63;

    unsigned short* crow = ctx + ((size_t)n * H_HEADS + h) * E_DIM + lane * 16;
    const int degree = deg[n];
    if (degree == 0) {
        ushort4 z4 = {0, 0, 0, 0};
#pragma unroll
        for (int j = 0; j < 4; ++j) ((ushort4*)crow)[j] = z4;
        return;
    }
    const int dv = degree < D_MAXN ? degree : D_MAXN;

    __shared__ int s_neigh[D_MAXN];
    if (t < dv) s_neigh[t] = neigh[n * D_MAXN + t];
    __syncthreads();

    float a[16];
    {
        const short8* ap = (const short8*)(Ahat + ((size_t)n * H_HEADS + h) * E_DIM + lane * 16);
        short8 v0 = ap[0], v1 = ap[1];
#pragma unroll
        for (int j = 0; j < 8; ++j) {
            a[j]     = bf2f((unsigned short)v0[j]);
            a[8 + j] = bf2f((unsigned short)v1[j]);
        }
    }

    float m = -3.4e38f, sum = 0.0f;
    float cacc[16];
#pragma unroll
    for (int i = 0; i < 16; ++i) cacc[i] = 0.0f;

    const float scale = 0.0625f;   // 1/sqrt(256)

    int d = 0;
    for (; d + 1 < dv; d += 2) {
        const ushort4* rp0 = (const ushort4*)(srcrel + (size_t)s_neigh[d]     * E_DIM + lane * 16);
        const ushort4* rp1 = (const ushort4*)(srcrel + (size_t)s_neigh[d + 1] * E_DIM + lane * 16);
        ushort4 w00 = rp0[0], w01 = rp0[1], w02 = rp0[2], w03 = rp0[3];
        ushort4 w10 = rp1[0], w11 = rp1[1], w12 = rp1[2], w13 = rp1[3];
        float e0[16], e1[16];
        e0[0]=bf2f(w00.x); e0[1]=bf2f(w00.y); e0[2]=bf2f(w00.z); e0[3]=bf2f(w00.w);
        e0[4]=bf2f(w01.x); e0[5]=bf2f(w01.y); e0[6]=bf2f(w01.z); e0[7]=bf2f(w01.w);
        e0[8]=bf2f(w02.x); e0[9]=bf2f(w02.y); e0[10]=bf2f(w02.z); e0[11]=bf2f(w02.w);
        e0[12]=bf2f(w03.x); e0[13]=bf2f(w03.y); e0[14]=bf2f(w03.z); e0[15]=bf2f(w03.w);
        e1[0]=bf2f(w10.x); e1[1]=bf2f(w10.y); e1[2]=bf2f(w10.z); e1[3]=bf2f(w10.w);
        e1[4]=bf2f(w11.x); e1[5]=bf2f(w11.y); e1[6]=bf2f(w11.z); e1[7]=bf2f(w11.w);
        e1[8]=bf2f(w12.x); e1[9]=bf2f(w12.y); e1[10]=bf2f(w12.z); e1[11]=bf2f(w12.w);
        e1[12]=bf2f(w13.x); e1[13]=bf2f(w13.y); e1[14]=bf2f(w13.z); e1[15]=bf2f(w13.w);

        float s0 = 0.0f, s1 = 0.0f;
#pragma unroll
        for (int i = 0; i < 16; ++i) { s0 = fmaf(a[i], e0[i], s0); s1 = fmaf(a[i], e1[i], s1); }
#pragma unroll
        for (int off = 32; off > 0; off >>= 1) {
            s0 += __shfl_xor(s0, off);
            s1 += __shfl_xor(s1, off);
        }
        s0 *= scale; s1 *= scale;

        if (s0 > m) {
            const float f = __expf(m - s0);
            sum *= f;
#pragma unroll
            for (int i = 0; i < 16; ++i) cacc[i] *= f;
            m = s0;
        }
        {
            const float wgt = __expf(s0 - m);
            sum += wgt;
#pragma unroll
            for (int i = 0; i < 16; ++i) cacc[i] = fmaf(wgt, e0[i], cacc[i]);
        }
        if (s1 > m) {
            const float f = __expf(m - s1);
            sum *= f;
#pragma unroll
            for (int i = 0; i < 16; ++i) cacc[i] *= f;
            m = s1;
        }
        {
            const float wgt = __expf(s1 - m);
            sum += wgt;
#pragma unroll
            for (int i = 0; i < 16; ++i) cacc[i] = fmaf(wgt, e1[i], cacc[i]);
        }
    }
    for (; d < dv; ++d) {
        const ushort4* rp = (const ushort4*)(srcrel + (size_t)s_neigh[d] * E_DIM + lane * 16);
        float e[16];
#pragma unroll
        for (int j = 0; j < 4; ++j) {
            ushort4 v = rp[j];
            e[j * 4 + 0] = bf2f(v.x); e[j * 4 + 1] = bf2f(v.y);
            e[j * 4 + 2] = bf2f(v.z); e[j * 4 + 3] = bf2f(v.w);
        }
        float s = 0.0f;
#pragma unroll
        for (int i = 0; i < 16; ++i) s = fmaf(a[i], e[i], s);
#pragma unroll
        for (int off = 32; off > 0; off >>= 1) s += __shfl_xor(s, off);
        s *= scale;
        if (s > m) {
            const float f = __expf(m - s);
            sum *= f;
#pragma unroll
            for (int i = 0; i < 16; ++i) cacc[i] *= f;
            m = s;
        }
        const float wgt = __expf(s - m);
        sum += wgt;
#pragma unroll
        for (int i = 0; i < 16; ++i) cacc[i] = fmaf(wgt, e[i], cacc[i]);
    }

    const float inv = 1.0f / sum;
#pragma unroll
    for (int j = 0; j < 4; ++j) {
        ushort4 o;
        o.x = f2bf(cacc[j * 4 + 0] * inv);
        o.y = f2bf(cacc[j * 4 + 1] * inv);
        o.z = f2bf(cacc[j * 4 + 2] * inv);
        o.w = f2bf(cacc[j * 4 + 3] * inv);
        ((ushort4*)crow)[j] = o;
    }
}

// ---------------------------------------------------------------------------
extern "C" void kernel_launch(void* const* d_in, const int* in_sizes, int n_in,
                              void* d_out, int out_size, void* d_ws, size_t ws_size,
                              hipStream_t stream)
{
    const float* target  = (const float*)d_in[0];   // [N, E]
    const float* source  = (const float*)d_in[1];   // [R, E]
    const float* adj     = (const float*)d_in[2];   // [N, R]
    const float* W_trans = (const float*)d_in[3];   // [E, E]
    const float* b_trans = (const float*)d_in[4];   // [E]
    const float* in_w    = (const float*)d_in[5];   // [3E, E]
    const float* in_b    = (const float*)d_in[6];   // [3E]
    const float* out_w   = (const float*)d_in[7];   // [E, E]
    const float* out_b   = (const float*)d_in[8];   // [E]
    float* out = (float*)d_out;                     // [N, E] f32

    char* ws = (char*)d_ws;
    unsigned short* src_bf    = (unsigned short*)ws; ws += (size_t)R_SRC * E_DIM * 2;
    unsigned short* wt_bf     = (unsigned short*)ws; ws += (size_t)E_DIM * E_DIM * 2;
    unsigned short* wv_bf     = (unsigned short*)ws; ws += (size_t)E_DIM * E_DIM * 2;
    unsigned short* outw_bf   = (unsigned short*)ws; ws += (size_t)E_DIM * E_DIM * 2;
    unsigned short* srcrel_bf = (unsigned short*)ws; ws += (size_t)R_SRC * E_DIM * 2;
    unsigned short* WkT_bf    = (unsigned short*)ws; ws += (size_t)H_HEADS * E_DIM * DH_DIM * 2;
    unsigned short* Q_bf      = (unsigned short*)ws; ws += (size_t)N_NODES * E_DIM * 2;
    unsigned short* Ahat_bf   = (unsigned short*)ws; ws += (size_t)N_NODES * H_HEADS * E_DIM * 2;
    unsigned short* ctx_bf    = (unsigned short*)ws; ws += (size_t)N_NODES * H_HEADS * E_DIM * 2;
    unsigned short* attn_bf   = (unsigned short*)ws; ws += (size_t)N_NODES * E_DIM * 2;
    int*            neigh     = (int*)ws;            ws += (size_t)N_NODES * D_MAXN * 4;
    int*            deg       = (int*)ws;            ws += (size_t)N_NODES * 4;

    const size_t EE = (size_t)E_DIM * E_DIM;

    // 1) pre-pass: Q GEMM + WkT transpose first, then neigh lists, then convs
    {
        ConvArgs a;
        const unsigned sz4[4] = {
            (unsigned)((size_t)R_SRC * E_DIM / 4),
            (unsigned)(EE / 4),
            (unsigned)(EE / 4),
            (unsigned)(EE / 4)};
        a.s[0] = source;        a.d[0] = src_bf;
        a.s[1] = W_trans;       a.d[1] = wt_bf;
        a.s[2] = in_w + 2 * EE; a.d[2] = wv_bf;     // Wv
        a.s[3] = out_w;         a.d[3] = outw_bf;
        a.off[0] = 0;
        for (int i = 0; i < 4; ++i) a.off[i + 1] = a.off[i] + sz4[i];
        pre_kernel<<<512 + N_NODES + NCONVB, 256, 0, stream>>>(
            adj, neigh, deg, a, in_w, target, in_b, WkT_bf, Q_bf);
    }

    // 2) src_relu = relu(source @ W_trans^T + b_trans)  [R, E] bf16 (256 blk)
    {
        GD ds;
        ds.A = src_bf; ds.B = wt_bf; ds.bias = b_trans; ds.C = srcrel_bf;
        ds.N = E_DIM; ds.K = E_DIM; ds.nbx = E_DIM / 256; ds.relu = 1; ds.outbf = 1;
        ds.rowmask = nullptr;
        const int sblocks = (R_SRC / 128) * (E_DIM / 256);   // 256
        gemm_t<128, 256><<<sblocks, 512, 0, stream>>>(ds, ds, sblocks);
    }

    // 3) Ahat_h = Q_h @ WkT_h   [N, H, E] bf16  (K=256, no bias; bk cancels)
    {
        GS g;
        g.A = Q_bf; g.B = WkT_bf; g.bias = nullptr; g.C = Ahat_bf;
        g.lda = E_DIM; g.ldb = DH_DIM; g.ldc = H_HEADS * E_DIM; g.K = DH_DIM;
        g.relu = 0; g.outbf = 1;
        g.azs = DH_DIM;
        g.bzs = (long long)E_DIM * DH_DIM;
        g.czs = E_DIM;
        g.bias_zs = 0; g.rowmask = nullptr;
        gemm_s<<<dim3(E_DIM / 64, N_NODES / 64, H_HEADS), 256, 0, stream>>>(g);
    }

    // 4) per-edge scores + softmax + ctx aggregation  [N, H, E] bf16
    gather_ctx<<<N_NODES, 256, 0, stream>>>(Ahat_bf, srcrel_bf, neigh, deg, ctx_bf);

    // 5) attn_h = CTX_h @ Wv_h^T + bv_h   [N, E] bf16
    {
        GS g;
        g.A = ctx_bf; g.B = wv_bf; g.bias = in_b + 2 * E_DIM; g.C = attn_bf;
        g.lda = H_HEADS * E_DIM; g.ldb = E_DIM; g.ldc = E_DIM; g.K = E_DIM;
        g.relu = 0; g.outbf = 1;
        g.azs = E_DIM;
        g.bzs = (long long)DH_DIM * E_DIM;
        g.czs = DH_DIM;
        g.bias_zs = DH_DIM; g.rowmask = nullptr;
        gemm_s<<<dim3(DH_DIM / 64, N_NODES / 64, H_HEADS), 256, 0, stream>>>(g);
    }

    // 6) out = attn @ out_w^T + out_b, deg==0 rows zeroed  [N, E] f32
    {
        GS g;
        g.A = attn_bf; g.B = outw_bf; g.bias = out_b; g.C = out;
        g.lda = E_DIM; g.ldb = E_DIM; g.ldc = E_DIM; g.K = E_DIM;
        g.relu = 0; g.outbf = 0; g.azs = 0; g.bzs = 0; g.czs = 0; g.bias_zs = 0;
        g.rowmask = deg;
        gemm_s<<<dim3(E_DIM / 64, N_NODES / 64, 1), 256, 0, stream>>>(g);
    }
}

// Round 23
// 103.934 us; speedup vs baseline: 1.2939x; 1.0105x over previous
//
#include <hip/hip_runtime.h>

#define N_NODES 1024
#define R_SRC   8192
#define E_DIM   1024
#define H_HEADS 4
#define DH_DIM  256
#define D_MAXN  48
#define NCONVB  1024   // grid-stride conversion blocks (8 f4/thread in flight)

typedef __attribute__((ext_vector_type(8))) short short8;
typedef __attribute__((ext_vector_type(4))) float f32x4;

__device__ __forceinline__ unsigned short f2bf(float f) {
    unsigned u = __float_as_uint(f);
    unsigned r = u + 0x7fffu + ((u >> 16) & 1u);   // round-to-nearest-even
    return (unsigned short)(r >> 16);
}
__device__ __forceinline__ float bf2f(unsigned short b) {
    return __uint_as_float(((unsigned)b) << 16);
}
__device__ __forceinline__ void gload16(const void* g, void* l) {
    __builtin_amdgcn_global_load_lds(
        (const __attribute__((address_space(1))) unsigned int*)g,
        (__attribute__((address_space(3))) unsigned int*)l,
        16, 0, 0);
}
template<int N> __device__ __forceinline__ void vwait() {
    if constexpr (N == 8)       asm volatile("s_waitcnt vmcnt(8)" ::: "memory");
    else if constexpr (N == 6)  asm volatile("s_waitcnt vmcnt(6)" ::: "memory");
    else if constexpr (N == 4)  asm volatile("s_waitcnt vmcnt(4)" ::: "memory");
    else if constexpr (N == 2)  asm volatile("s_waitcnt vmcnt(2)" ::: "memory");
    else                        asm volatile("s_waitcnt vmcnt(0)" ::: "memory");
}

// ===========================================================================
// Deep-pipelined bf16 MFMA NT GEMM, 128x256 tile, BK=64, 512 threads=8 waves.
// 3-buffer LDS rotation, issue-early staging, counted vmcnt, raw barriers.
// Used ONLY for the big src_relu GEMM (256 blocks, exact 1/CU fill).
// ===========================================================================
struct GD {
    const unsigned short* A;
    const unsigned short* B;
    const float* bias;
    void* C;
    int N, K, nbx, relu, outbf;
    const int* rowmask;
};

template<int BM, int BN>
__global__ __launch_bounds__(512) void gemm_t(GD d0, GD d1, int split)
{
    constexpr int AI = BM / 64;
    constexpr int BI = BN / 64;
    constexpr int VN = AI + BI;
    constexpr int FM = BM / 32;
    constexpr int FN = BN / 64;

    __shared__ __align__(16) unsigned short lds[3][(BM + BN) * 64];

    int bid = blockIdx.x;
    const int nwg = gridDim.x;
    bid = (bid & 7) * (nwg >> 3) + (bid >> 3);   // XCD swizzle (nwg%8==0)

    GD d; int q;
    if (bid < split) { d = d0; q = bid; }
    else             { d = d1; q = bid - split; }
    const int m0 = (q / d.nbx) * BM;
    const int n0 = (q % d.nbx) * BN;
    const int K  = d.K;

    const int t = threadIdx.x;
    const int w = t >> 6, l = t & 63;
    const int wm = w >> 2, wn = w & 3;

    const int trow = t >> 3, tkc = t & 7;
    const int tswz = tkc ^ (trow & 7);           // pre-swizzled global src
    const unsigned short* gA[AI];
    const unsigned short* gB[BI];
#pragma unroll
    for (int i = 0; i < AI; ++i)
        gA[i] = d.A + (size_t)(m0 + i * 64 + trow) * K + tswz * 8;
#pragma unroll
    for (int i = 0; i < BI; ++i)
        gB[i] = d.B + (size_t)(n0 + i * 64 + trow) * K + tswz * 8;

    f32x4 acc[FM][FN] = {};

    auto STAGE = [&](int c, int kt) {
        const int ko = kt * 64;
#pragma unroll
        for (int i = 0; i < AI; ++i)
            gload16(gA[i] + ko, &lds[c][(i * 512 + t) * 8]);
#pragma unroll
        for (int i = 0; i < BI; ++i)
            gload16(gB[i] + ko, &lds[c][BM * 64 + (i * 512 + t) * 8]);
    };

    const int nt = K / 64;
    STAGE(0, 0);
    STAGE(1, 1);
    vwait<VN>();
    __builtin_amdgcn_s_barrier();

    const int lr = l & 15, hi = l >> 4;
    const int rsw = l & 7;
    const int cs0 = ((0 + hi) ^ rsw) * 8;
    const int cs1 = ((4 + hi) ^ rsw) * 8;
    const int abase = (wm * (BM / 2) + lr) * 64;
    const int bbase = BM * 64 + (wn * 64 + lr) * 64;

    for (int kt = 0; kt < nt; ++kt) {
        const int cur = kt % 3;
        if (kt + 2 < nt) STAGE((kt + 2) % 3, kt + 2);   // issue-early

        const unsigned short* Ls = &lds[cur][0];

        short8 bv[FN][2];
#pragma unroll
        for (int fj = 0; fj < FN; ++fj) {
            bv[fj][0] = *(const short8*)&Ls[bbase + fj * 1024 + cs0];
            bv[fj][1] = *(const short8*)&Ls[bbase + fj * 1024 + cs1];
        }
#pragma unroll
        for (int g = 0; g < FM; g += 4) {
            short8 av[4][2];
#pragma unroll
            for (int fi = 0; fi < 4; ++fi) {
                av[fi][0] = *(const short8*)&Ls[abase + (g + fi) * 1024 + cs0];
                av[fi][1] = *(const short8*)&Ls[abase + (g + fi) * 1024 + cs1];
            }
            __builtin_amdgcn_s_setprio(1);
#pragma unroll
            for (int ks = 0; ks < 2; ++ks)
#pragma unroll
                for (int fi = 0; fi < 4; ++fi)
#pragma unroll
                    for (int fj = 0; fj < FN; ++fj)
                        acc[g + fi][fj] = __builtin_amdgcn_mfma_f32_16x16x32_bf16(
                            av[fi][ks], bv[fj][ks], acc[g + fi][fj], 0, 0, 0);
            __builtin_amdgcn_s_setprio(0);
        }

        asm volatile("" ::: "memory");
        __builtin_amdgcn_s_barrier();
        if (kt + 2 < nt) {
            vwait<VN>();
        } else {
            vwait<0>();
        }
        __builtin_amdgcn_s_barrier();
    }

#pragma unroll
    for (int fj = 0; fj < FN; ++fj) {
        const int c = n0 + wn * 64 + fj * 16 + lr;
        const float bvs = d.bias[c];
#pragma unroll
        for (int fi = 0; fi < FM; ++fi) {
            const int rb = m0 + wm * (BM / 2) + fi * 16 + hi * 4;
#pragma unroll
            for (int qq = 0; qq < 4; ++qq) {
                const int r = rb + qq;
                float x = acc[fi][fj][qq] + bvs;
                if (d.relu) x = fmaxf(x, 0.0f);
                if (d.rowmask && d.rowmask[r] == 0) x = 0.0f;
                if (d.outbf) ((unsigned short*)d.C)[(size_t)r * d.N + c] = f2bf(x);
                else         ((float*)d.C)[(size_t)r * d.N + c] = x;
            }
        }
    }
}

// ===========================================================================
// Pipelined strided small GEMM (64x64 tile, 256 threads, BK=32), 3-buffer
// rotation + issue-early + counted vmcnt(2) + raw barriers. Per-grid.z offs.
// ===========================================================================
struct GS {
    const unsigned short* A;
    const unsigned short* B;
    const float* bias;        // nullable
    void* C;
    int lda, ldb, ldc, K, relu, outbf;
    long long azs, bzs, czs;  // per-z element offsets
    int bias_zs;
    const int* rowmask;       // nullable (indexed by output row)
};

__global__ __launch_bounds__(256) void gemm_s(GS g)
{
    const int z = blockIdx.z;
    const unsigned short* A = g.A + (size_t)((long long)z * g.azs);
    const unsigned short* B = g.B + (size_t)((long long)z * g.bzs);
    const float* bias = g.bias ? g.bias + (size_t)z * g.bias_zs : nullptr;

    __shared__ __align__(16) unsigned short S[3][128 * 32];   // 24 KB

    const int t = threadIdx.x;
    const int m0 = blockIdx.y * 64;
    const int n0 = blockIdx.x * 64;
    const int w = t >> 6, l = t & 63;
    const int wrow = (w >> 1) * 32;
    const int wcol = (w & 1) * 32;
    const int lr = l & 15;
    const int kg = (l >> 4) * 8;

    f32x4 acc[2][2] = {};

    const unsigned short* gp0 = A + (size_t)(m0 + (t >> 2)) * g.lda + (t & 3) * 8;
    const unsigned short* gp1 = B + (size_t)(n0 + (t >> 2)) * g.ldb + (t & 3) * 8;

    auto STAGE = [&](int c, int k0) {
        gload16(gp0 + k0, &S[c][t * 8]);
        gload16(gp1 + k0, &S[c][2048 + t * 8]);
    };

    const int nt = g.K / 32;
    STAGE(0, 0);
    STAGE(1, 32);
    vwait<2>();
    __builtin_amdgcn_s_barrier();

    for (int kt = 0; kt < nt; ++kt) {
        const int cur = kt % 3;
        if (kt + 2 < nt) STAGE((kt + 2) % 3, (kt + 2) * 32);   // issue-early

        const unsigned short* Ls = &S[cur][0];

        short8 af[2], bw[2];
#pragma unroll
        for (int i = 0; i < 2; ++i)
            af[i] = *(const short8*)&Ls[(wrow + i * 16 + lr) * 32 + kg];
#pragma unroll
        for (int j = 0; j < 2; ++j)
            bw[j] = *(const short8*)&Ls[2048 + (wcol + j * 16 + lr) * 32 + kg];
#pragma unroll
        for (int i = 0; i < 2; ++i)
#pragma unroll
            for (int j = 0; j < 2; ++j)
                acc[i][j] = __builtin_amdgcn_mfma_f32_16x16x32_bf16(
                    af[i], bw[j], acc[i][j], 0, 0, 0);

        asm volatile("" ::: "memory");
        __builtin_amdgcn_s_barrier();
        if (kt + 2 < nt) {
            vwait<2>();
        } else {
            vwait<0>();
        }
        __builtin_amdgcn_s_barrier();
    }

#pragma unroll
    for (int j = 0; j < 2; ++j) {
        const int c = n0 + wcol + j * 16 + lr;
        const float bv = bias ? bias[c] : 0.0f;
#pragma unroll
        for (int i = 0; i < 2; ++i) {
            const int rbase = m0 + wrow + i * 16 + (l >> 4) * 4;
#pragma unroll
            for (int qq = 0; qq < 4; ++qq) {
                const int r = rbase + qq;
                float x = acc[i][j][qq] + bv;
                if (g.relu) x = fmaxf(x, 0.0f);
                if (g.rowmask && g.rowmask[r] == 0) x = 0.0f;
                if (g.outbf)
                    ((unsigned short*)g.C)[(size_t)((long long)z * g.czs) + (size_t)r * g.ldc + c] = f2bf(x);
                else
                    ((float*)g.C)[(size_t)((long long)z * g.czs) + (size_t)r * g.ldc + c] = x;
            }
        }
    }
}

// ---------------------------------------------------------------------------
// Fused pre-pass. Heavy blocks FIRST:
//   [0, 256)           : Q = target @ Wq^T + bq (fp32-direct, 64x64, BK=32)
//   [256, 512)         : Wk transpose -> WkT[h][e][d] bf16
//   [512, 512+N)       : neighbor lists (float4 scan: 1 load/lane/window)
//   [512+N, +NCONVB)   : fp32->bf16 conversions, grid-stride, 8 f4/thread
// Single UNION shared buffer (16.6 KB).
// ---------------------------------------------------------------------------
struct ConvArgs {
    const float* s[4];
    unsigned short* d[4];
    unsigned off[5];
};

__global__ __launch_bounds__(256) void pre_kernel(
    const float* __restrict__ adj, int* __restrict__ neigh, int* __restrict__ deg,
    ConvArgs a, const float* __restrict__ inw_f, const float* __restrict__ tgt_f,
    const float* __restrict__ in_b, unsigned short* __restrict__ WkT,
    unsigned short* __restrict__ Q_bf)
{
    __shared__ __align__(16) unsigned char smem[64 * 65 * 4];   // 16.6 KB union
    const int t = threadIdx.x;

    if (blockIdx.x < 256) {
        // ---- Q GEMM (fp32 direct): 64x64 tile, K=1024, BK=32
        unsigned short (*QS)[64 * 32] = (unsigned short (*)[64 * 32])smem;
        const int qb = blockIdx.x;
        const int m0 = (qb >> 4) * 64;
        const int n0 = (qb & 15) * 64;
        const int w = t >> 6, l = t & 63;
        const int wrow = (w >> 1) * 32;
        const int wcol = (w & 1) * 32;
        const int lr = l & 15;
        const int kg = (l >> 4) * 8;
        const int row = t >> 2, k8 = (t & 3) * 8;

        const float* ga = tgt_f + (size_t)(m0 + row) * E_DIM + k8;
        const float* gb = inw_f + (size_t)(n0 + row) * E_DIM + k8;   // Wq rows

        f32x4 acc[2][2] = {};

        for (int k0 = 0; k0 < E_DIM; k0 += 32) {
            float4 a0 = *(const float4*)(ga + k0);
            float4 a1 = *(const float4*)(ga + k0 + 4);
            float4 b0 = *(const float4*)(gb + k0);
            float4 b1 = *(const float4*)(gb + k0 + 4);
            short8 av, bv;
            av[0] = (short)f2bf(a0.x); av[1] = (short)f2bf(a0.y);
            av[2] = (short)f2bf(a0.z); av[3] = (short)f2bf(a0.w);
            av[4] = (short)f2bf(a1.x); av[5] = (short)f2bf(a1.y);
            av[6] = (short)f2bf(a1.z); av[7] = (short)f2bf(a1.w);
            bv[0] = (short)f2bf(b0.x); bv[1] = (short)f2bf(b0.y);
            bv[2] = (short)f2bf(b0.z); bv[3] = (short)f2bf(b0.w);
            bv[4] = (short)f2bf(b1.x); bv[5] = (short)f2bf(b1.y);
            bv[6] = (short)f2bf(b1.z); bv[7] = (short)f2bf(b1.w);
            *(short8*)&QS[0][row * 32 + k8] = av;
            *(short8*)&QS[1][row * 32 + k8] = bv;
            __syncthreads();

            short8 af[2], bw[2];
#pragma unroll
            for (int i = 0; i < 2; ++i)
                af[i] = *(const short8*)&QS[0][(wrow + i * 16 + lr) * 32 + kg];
#pragma unroll
            for (int j = 0; j < 2; ++j)
                bw[j] = *(const short8*)&QS[1][(wcol + j * 16 + lr) * 32 + kg];
#pragma unroll
            for (int i = 0; i < 2; ++i)
#pragma unroll
                for (int j = 0; j < 2; ++j)
                    acc[i][j] = __builtin_amdgcn_mfma_f32_16x16x32_bf16(
                        af[i], bw[j], acc[i][j], 0, 0, 0);
            __syncthreads();
        }

#pragma unroll
        for (int j = 0; j < 2; ++j) {
            const int c = n0 + wcol + j * 16 + lr;
            const float bv = in_b[c];
#pragma unroll
            for (int i = 0; i < 2; ++i) {
                const int rbase = m0 + wrow + i * 16 + (l >> 4) * 4;
#pragma unroll
                for (int qq = 0; qq < 4; ++qq)
                    Q_bf[(size_t)(rbase + qq) * E_DIM + c] = f2bf(acc[i][j][qq] + bv);
            }
        }
        return;
    }

    if (blockIdx.x < 512) {
        // ---- Wk transpose: tile 64(e) x 64(d) per block
        float (*tile)[65] = (float (*)[65])smem;
        const int tb = blockIdx.x - 256;
        const int h = tb >> 6, rem = tb & 63;
        const int e0 = (rem >> 2) * 64, d0 = (rem & 3) * 64;
        const int r = t >> 2, c4 = (t & 3) * 16;
        const float* tsrc = inw_f + (size_t)(E_DIM + h * 256 + d0 + r) * E_DIM + e0 + c4;
#pragma unroll
        for (int jj = 0; jj < 4; ++jj) {
            float4 v = ((const float4*)tsrc)[jj];
            tile[r][c4 + jj * 4 + 0] = v.x;
            tile[r][c4 + jj * 4 + 1] = v.y;
            tile[r][c4 + jj * 4 + 2] = v.z;
            tile[r][c4 + jj * 4 + 3] = v.w;
        }
        __syncthreads();
        const int er = t >> 2, dc = (t & 3) * 16;
        unsigned short* wout = WkT + ((size_t)h * E_DIM + e0 + er) * 256 + d0 + dc;
#pragma unroll
        for (int jj = 0; jj < 4; ++jj) {
            ushort4 o;
            o.x = f2bf(tile[dc + jj * 4 + 0][er]);
            o.y = f2bf(tile[dc + jj * 4 + 1][er]);
            o.z = f2bf(tile[dc + jj * 4 + 2][er]);
            o.w = f2bf(tile[dc + jj * 4 + 3][er]);
            ((ushort4*)wout)[jj] = o;
        }
        return;
    }

    if (blockIdx.x < (unsigned)(512 + N_NODES)) {
        // ---- neighbor lists: 4 waves; wave w owns cols [w*2048,(w+1)*2048).
        // float4 scan: lane l owns cols base+4l..+3 of each 256-col window.
        // Ascending-column rank(l,j) = total + (all set bits in lanes < l)
        //                              + (set bits j' < j within this lane).
        int* s_cnt = (int*)smem;
        int (*s_idx)[D_MAXN] = (int (*)[D_MAXN])(smem + 16);

        const int n    = blockIdx.x - 512;
        const int w    = t >> 6;
        const int lane = t & 63;
        const float* row = adj + (size_t)n * R_SRC;

        const int seg0 = w * (R_SRC / 4);
        const unsigned long long lower = (1ULL << lane) - 1ULL;
        int total = 0;

        for (int base = seg0; base < seg0 + R_SRC / 4; base += 256) {
            const float4 v = *(const float4*)(row + base + lane * 4);
            const int b0 = (v.x != 0.0f), b1 = (v.y != 0.0f);
            const int b2 = (v.z != 0.0f), b3 = (v.w != 0.0f);
            const unsigned long long m0 = __ballot(b0);
            const unsigned long long m1 = __ballot(b1);
            const unsigned long long m2 = __ballot(b2);
            const unsigned long long m3 = __ballot(b3);
            int p = total + __popcll(m0 & lower) + __popcll(m1 & lower)
                          + __popcll(m2 & lower) + __popcll(m3 & lower);
            const int col = base + lane * 4;
            if (b0 && p < D_MAXN) s_idx[w][p] = col + 0;  p += b0;
            if (b1 && p < D_MAXN) s_idx[w][p] = col + 1;  p += b1;
            if (b2 && p < D_MAXN) s_idx[w][p] = col + 2;  p += b2;
            if (b3 && p < D_MAXN) s_idx[w][p] = col + 3;  p += b3;
            total += __popcll(m0) + __popcll(m1) + __popcll(m2) + __popcll(m3);
        }
        if (lane == 0) s_cnt[w] = total;
        __syncthreads();

        int start = 0;
#pragma unroll
        for (int i = 0; i < 4; ++i) if (i < w) start += s_cnt[i];
        const int degree = s_cnt[0] + s_cnt[1] + s_cnt[2] + s_cnt[3];
        const int nstore = total < D_MAXN ? total : D_MAXN;
        if (lane < nstore) {
            const int gpos = start + lane;
            if (gpos < D_MAXN) neigh[n * D_MAXN + gpos] = s_idx[w][lane];
        }
        if (t == 0) deg[n] = degree;
        return;
    }

    // ---- conversions: grid-stride, 8 float4 per thread per iteration
    {
        const unsigned total = a.off[4];
        const unsigned stride = NCONVB * 2048;           // f4 per sweep
        for (unsigned bs = (blockIdx.x - 512 - N_NODES) * 2048; bs < total; bs += stride) {
            float4 v[8];
            unsigned idx[8];
            int ok[8];
#pragma unroll
            for (int j = 0; j < 8; ++j) {
                idx[j] = bs + j * 256 + t;
                ok[j] = idx[j] < total;
            }
            int seg[8];
#pragma unroll
            for (int j = 0; j < 8; ++j) {
                seg[j] = 0;
#pragma unroll
                for (int s = 1; s < 4; ++s) seg[j] += (idx[j] >= a.off[s]);
            }
#pragma unroll
            for (int j = 0; j < 8; ++j)
                if (ok[j]) v[j] = ((const float4*)a.s[seg[j]])[idx[j] - a.off[seg[j]]];
#pragma unroll
            for (int j = 0; j < 8; ++j) {
                if (ok[j]) {
                    ushort4 o;
                    o.x = f2bf(v[j].x); o.y = f2bf(v[j].y);
                    o.z = f2bf(v[j].z); o.w = f2bf(v[j].w);
                    ((ushort4*)a.d[seg[j]])[idx[j] - a.off[seg[j]]] = o;
                }
            }
        }
    }
}

// ---------------------------------------------------------------------------
// Fused per-edge scores + online softmax + context aggregation.
// Block = node, wave h = head, lane owns 16 contiguous dims. 2-edge unroll.
// Ahat is bf16 (halves its HBM traffic; softmax margin tolerates rounding).
// ---------------------------------------------------------------------------
__global__ __launch_bounds__(256) void gather_ctx(
    const unsigned short* __restrict__ Ahat, const unsigned short* __restrict__ srcrel,
    const int* __restrict__ neigh, const int* __restrict__ deg,
    unsigned short* __restrict__ ctx)
{
    const int n = blockIdx.x;
    const int t = threadIdx.x;
    const int h = t >> 6;
    const int lane = t & 63;

    unsigned short* crow = ctx + ((size_t)n * H_HEADS + h) * E_DIM + lane * 16;
    const int degree = deg[n];
    if (degree == 0) {
        ushort4 z4 = {0, 0, 0, 0};
#pragma unroll
        for (int j = 0; j < 4; ++j) ((ushort4*)crow)[j] = z4;
        return;
    }
    const int dv = degree < D_MAXN ? degree : D_MAXN;

    __shared__ int s_neigh[D_MAXN];
    if (t < dv) s_neigh[t] = neigh[n * D_MAXN + t];
    __syncthreads();

    float a[16];
    {
        const short8* ap = (const short8*)(Ahat + ((size_t)n * H_HEADS + h) * E_DIM + lane * 16);
        short8 v0 = ap[0], v1 = ap[1];
#pragma unroll
        for (int j = 0; j < 8; ++j) {
            a[j]     = bf2f((unsigned short)v0[j]);
            a[8 + j] = bf2f((unsigned short)v1[j]);
        }
    }

    float m = -3.4e38f, sum = 0.0f;
    float cacc[16];
#pragma unroll
    for (int i = 0; i < 16; ++i) cacc[i] = 0.0f;

    const float scale = 0.0625f;   // 1/sqrt(256)

    int d = 0;
    for (; d + 1 < dv; d += 2) {
        const ushort4* rp0 = (const ushort4*)(srcrel + (size_t)s_neigh[d]     * E_DIM + lane * 16);
        const ushort4* rp1 = (const ushort4*)(srcrel + (size_t)s_neigh[d + 1] * E_DIM + lane * 16);
        ushort4 w00 = rp0[0], w01 = rp0[1], w02 = rp0[2], w03 = rp0[3];
        ushort4 w10 = rp1[0], w11 = rp1[1], w12 = rp1[2], w13 = rp1[3];
        float e0[16], e1[16];
        e0[0]=bf2f(w00.x); e0[1]=bf2f(w00.y); e0[2]=bf2f(w00.z); e0[3]=bf2f(w00.w);
        e0[4]=bf2f(w01.x); e0[5]=bf2f(w01.y); e0[6]=bf2f(w01.z); e0[7]=bf2f(w01.w);
        e0[8]=bf2f(w02.x); e0[9]=bf2f(w02.y); e0[10]=bf2f(w02.z); e0[11]=bf2f(w02.w);
        e0[12]=bf2f(w03.x); e0[13]=bf2f(w03.y); e0[14]=bf2f(w03.z); e0[15]=bf2f(w03.w);
        e1[0]=bf2f(w10.x); e1[1]=bf2f(w10.y); e1[2]=bf2f(w10.z); e1[3]=bf2f(w10.w);
        e1[4]=bf2f(w11.x); e1[5]=bf2f(w11.y); e1[6]=bf2f(w11.z); e1[7]=bf2f(w11.w);
        e1[8]=bf2f(w12.x); e1[9]=bf2f(w12.y); e1[10]=bf2f(w12.z); e1[11]=bf2f(w12.w);
        e1[12]=bf2f(w13.x); e1[13]=bf2f(w13.y); e1[14]=bf2f(w13.z); e1[15]=bf2f(w13.w);

        float s0 = 0.0f, s1 = 0.0f;
#pragma unroll
        for (int i = 0; i < 16; ++i) { s0 = fmaf(a[i], e0[i], s0); s1 = fmaf(a[i], e1[i], s1); }
#pragma unroll
        for (int off = 32; off > 0; off >>= 1) {
            s0 += __shfl_xor(s0, off);
            s1 += __shfl_xor(s1, off);
        }
        s0 *= scale; s1 *= scale;

        if (s0 > m) {
            const float f = __expf(m - s0);
            sum *= f;
#pragma unroll
            for (int i = 0; i < 16; ++i) cacc[i] *= f;
            m = s0;
        }
        {
            const float wgt = __expf(s0 - m);
            sum += wgt;
#pragma unroll
            for (int i = 0; i < 16; ++i) cacc[i] = fmaf(wgt, e0[i], cacc[i]);
        }
        if (s1 > m) {
            const float f = __expf(m - s1);
            sum *= f;
#pragma unroll
            for (int i = 0; i < 16; ++i) cacc[i] *= f;
            m = s1;
        }
        {
            const float wgt = __expf(s1 - m);
            sum += wgt;
#pragma unroll
            for (int i = 0; i < 16; ++i) cacc[i] = fmaf(wgt, e1[i], cacc[i]);
        }
    }
    for (; d < dv; ++d) {
        const ushort4* rp = (const ushort4*)(srcrel + (size_t)s_neigh[d] * E_DIM + lane * 16);
        float e[16];
#pragma unroll
        for (int j = 0; j < 4; ++j) {
            ushort4 v = rp[j];
            e[j * 4 + 0] = bf2f(v.x); e[j * 4 + 1] = bf2f(v.y);
            e[j * 4 + 2] = bf2f(v.z); e[j * 4 + 3] = bf2f(v.w);
        }
        float s = 0.0f;
#pragma unroll
        for (int i = 0; i < 16; ++i) s = fmaf(a[i], e[i], s);
#pragma unroll
        for (int off = 32; off > 0; off >>= 1) s += __shfl_xor(s, off);
        s *= scale;
        if (s > m) {
            const float f = __expf(m - s);
            sum *= f;
#pragma unroll
            for (int i = 0; i < 16; ++i) cacc[i] *= f;
            m = s;
        }
        const float wgt = __expf(s - m);
        sum += wgt;
#pragma unroll
        for (int i = 0; i < 16; ++i) cacc[i] = fmaf(wgt, e[i], cacc[i]);
    }

    const float inv = 1.0f / sum;
#pragma unroll
    for (int j = 0; j < 4; ++j) {
        ushort4 o;
        o.x = f2bf(cacc[j * 4 + 0] * inv);
        o.y = f2bf(cacc[j * 4 + 1] * inv);
        o.z = f2bf(cacc[j * 4 + 2] * inv);
        o.w = f2bf(cacc[j * 4 + 3] * inv);
        ((ushort4*)crow)[j] = o;
    }
}

// ---------------------------------------------------------------------------
extern "C" void kernel_launch(void* const* d_in, const int* in_sizes, int n_in,
                              void* d_out, int out_size, void* d_ws, size_t ws_size,
                              hipStream_t stream)
{
    const float* target  = (const float*)d_in[0];   // [N, E]
    const float* source  = (const float*)d_in[1];   // [R, E]
    const float* adj     = (const float*)d_in[2];   // [N, R]
    const float* W_trans = (const float*)d_in[3];   // [E, E]
    const float* b_trans = (const float*)d_in[4];   // [E]
    const float* in_w    = (const float*)d_in[5];   // [3E, E]
    const float* in_b    = (const float*)d_in[6];   // [3E]
    const float* out_w   = (const float*)d_in[7];   // [E, E]
    const float* out_b   = (const float*)d_in[8];   // [E]
    float* out = (float*)d_out;                     // [N, E] f32

    char* ws = (char*)d_ws;
    unsigned short* src_bf    = (unsigned short*)ws; ws += (size_t)R_SRC * E_DIM * 2;
    unsigned short* wt_bf     = (unsigned short*)ws; ws += (size_t)E_DIM * E_DIM * 2;
    unsigned short* wv_bf     = (unsigned short*)ws; ws += (size_t)E_DIM * E_DIM * 2;
    unsigned short* outw_bf   = (unsigned short*)ws; ws += (size_t)E_DIM * E_DIM * 2;
    unsigned short* srcrel_bf = (unsigned short*)ws; ws += (size_t)R_SRC * E_DIM * 2;
    unsigned short* WkT_bf    = (unsigned short*)ws; ws += (size_t)H_HEADS * E_DIM * DH_DIM * 2;
    unsigned short* Q_bf      = (unsigned short*)ws; ws += (size_t)N_NODES * E_DIM * 2;
    unsigned short* Ahat_bf   = (unsigned short*)ws; ws += (size_t)N_NODES * H_HEADS * E_DIM * 2;
    unsigned short* ctx_bf    = (unsigned short*)ws; ws += (size_t)N_NODES * H_HEADS * E_DIM * 2;
    unsigned short* attn_bf   = (unsigned short*)ws; ws += (size_t)N_NODES * E_DIM * 2;
    int*            neigh     = (int*)ws;            ws += (size_t)N_NODES * D_MAXN * 4;
    int*            deg       = (int*)ws;            ws += (size_t)N_NODES * 4;

    const size_t EE = (size_t)E_DIM * E_DIM;

    // 1) pre-pass: Q GEMM + WkT transpose first, then neigh lists, then convs
    {
        ConvArgs a;
        const unsigned sz4[4] = {
            (unsigned)((size_t)R_SRC * E_DIM / 4),
            (unsigned)(EE / 4),
            (unsigned)(EE / 4),
            (unsigned)(EE / 4)};
        a.s[0] = source;        a.d[0] = src_bf;
        a.s[1] = W_trans;       a.d[1] = wt_bf;
        a.s[2] = in_w + 2 * EE; a.d[2] = wv_bf;     // Wv
        a.s[3] = out_w;         a.d[3] = outw_bf;
        a.off[0] = 0;
        for (int i = 0; i < 4; ++i) a.off[i + 1] = a.off[i] + sz4[i];
        pre_kernel<<<512 + N_NODES + NCONVB, 256, 0, stream>>>(
            adj, neigh, deg, a, in_w, target, in_b, WkT_bf, Q_bf);
    }

    // 2) src_relu = relu(source @ W_trans^T + b_trans)  [R, E] bf16 (256 blk)
    {
        GD ds;
        ds.A = src_bf; ds.B = wt_bf; ds.bias = b_trans; ds.C = srcrel_bf;
        ds.N = E_DIM; ds.K = E_DIM; ds.nbx = E_DIM / 256; ds.relu = 1; ds.outbf = 1;
        ds.rowmask = nullptr;
        const int sblocks = (R_SRC / 128) * (E_DIM / 256);   // 256
        gemm_t<128, 256><<<sblocks, 512, 0, stream>>>(ds, ds, sblocks);
    }

    // 3) Ahat_h = Q_h @ WkT_h   [N, H, E] bf16  (K=256, no bias; bk cancels)
    {
        GS g;
        g.A = Q_bf; g.B = WkT_bf; g.bias = nullptr; g.C = Ahat_bf;
        g.lda = E_DIM; g.ldb = DH_DIM; g.ldc = H_HEADS * E_DIM; g.K = DH_DIM;
        g.relu = 0; g.outbf = 1;
        g.azs = DH_DIM;
        g.bzs = (long long)E_DIM * DH_DIM;
        g.czs = E_DIM;
        g.bias_zs = 0; g.rowmask = nullptr;
        gemm_s<<<dim3(E_DIM / 64, N_NODES / 64, H_HEADS), 256, 0, stream>>>(g);
    }

    // 4) per-edge scores + softmax + ctx aggregation  [N, H, E] bf16
    gather_ctx<<<N_NODES, 256, 0, stream>>>(Ahat_bf, srcrel_bf, neigh, deg, ctx_bf);

    // 5) attn_h = CTX_h @ Wv_h^T + bv_h   [N, E] bf16
    {
        GS g;
        g.A = ctx_bf; g.B = wv_bf; g.bias = in_b + 2 * E_DIM; g.C = attn_bf;
        g.lda = H_HEADS * E_DIM; g.ldb = E_DIM; g.ldc = E_DIM; g.K = E_DIM;
        g.relu = 0; g.outbf = 1;
        g.azs = E_DIM;
        g.bzs = (long long)DH_DIM * E_DIM;
        g.czs = DH_DIM;
        g.bias_zs = DH_DIM; g.rowmask = nullptr;
        gemm_s<<<dim3(DH_DIM / 64, N_NODES / 64, H_HEADS), 256, 0, stream>>>(g);
    }

    // 6) out = attn @ out_w^T + out_b, deg==0 rows zeroed  [N, E] f32
    {
        GS g;
        g.A = attn_bf; g.B = outw_bf; g.bias = out_b; g.C = out;
        g.lda = E_DIM; g.ldb = E_DIM; g.ldc = E_DIM; g.K = E_DIM;
        g.relu = 0; g.outbf = 0; g.azs = 0; g.bzs = 0; g.czs = 0; g.bias_zs = 0;
        g.rowmask = deg;
        gemm_s<<<dim3(E_DIM / 64, N_NODES / 64, 1), 256, 0, stream>>>(g);
    }
}